// Round 9
// baseline (891.363 us; speedup 1.0000x reference)
//
#include <hip/hip_runtime.h>

typedef unsigned short u16;
typedef unsigned int u32;
typedef __bf16 bf16x8 __attribute__((ext_vector_type(8)));
typedef float f32x4 __attribute__((ext_vector_type(4)));
typedef u16 u16x4 __attribute__((ext_vector_type(4)));
typedef u16 u16x8 __attribute__((ext_vector_type(8)));
typedef int i32x4 __attribute__((ext_vector_type(4)));

#define N_TW 1024
#define L_TOK 64
#define M1 (N_TW * L_TOK)

__device__ __forceinline__ u16 f2bf(float f) {
  u32 u = __builtin_bit_cast(u32, f);
  u += 0x7fffu + ((u >> 16) & 1u);
  return (u16)(u >> 16);
}
__device__ __forceinline__ float bf2f(u16 b) {
  u32 u = ((u32)b) << 16;
  return __builtin_bit_cast(float, u);
}
__device__ __forceinline__ void gl_lds16(const void* g, void* l) {
  __builtin_amdgcn_global_load_lds((const __attribute__((address_space(1))) u32*)g,
                                   (__attribute__((address_space(3))) u32*)l, 16, 0, 0);
}
__device__ __forceinline__ float sigf(float x) { return 1.f / (1.f + __expf(-x)); }
__device__ __forceinline__ float tanh_(float x) { return 1.f - 2.f / (__expf(2.f * x) + 1.f); }

// ---------------- prep: fp32 -> bf16 weight conversion ----------------
__global__ __launch_bounds__(256) void k_f2bf(const float* __restrict__ s, u16* __restrict__ d, int n) {
  int i = (blockIdx.x * 256 + threadIdx.x) * 4;
  if (i < n) {
    float4 v = *(const float4*)(s + i);
    u16x4 o;
    o.x = f2bf(v.x); o.y = f2bf(v.y); o.z = f2bf(v.z); o.w = f2bf(v.w);
    *(u16x4*)(d + i) = o;
  }
}

__global__ __launch_bounds__(256) void k_bias(const float* __restrict__ a, const float* __restrict__ b,
                                              const float* __restrict__ c, const float* __restrict__ d,
                                              float* __restrict__ o) {
  int i = blockIdx.x * 256 + threadIdx.x;  // 0..2047
  o[i] = (i < 1024) ? (a[i] + b[i]) : (c[i - 1024] + d[i - 1024]);
}

// ---------------- Whh pack into per-(wave16) MFMA fragment order ----------------
// WP2[dir][w(16)][s(8)][g(4)][l(64)][i(8)]: lane l of fragment (w,s,g) holds
// B[gate=g][h = w*16 + (l&15)][k = s*32 + (l>>4)*8 + i].
__global__ __launch_bounds__(256) void k_prep_wp2(const float* __restrict__ Wf, const float* __restrict__ Wb,
                                                  u16* __restrict__ P) {
  int e = blockIdx.x * 256 + threadIdx.x;  // 0..524287
  int i = e & 7, l = (e >> 3) & 63, g = (e >> 9) & 3, s = (e >> 11) & 7, w = (e >> 14) & 15, dir = e >> 18;
  int h = w * 16 + (l & 15), k = s * 32 + ((l >> 4) << 3) + i;
  const float* W = dir ? Wb : Wf;
  P[e] = f2bf(W[(g * 256 + h) * 256 + k]);
}

// ---------------- embedding gather + bf16 convert ----------------
__global__ __launch_bounds__(256) void k_gather(const int* __restrict__ tok, const float* __restrict__ emb,
                                                u16* __restrict__ x) {
  long long t = (long long)blockIdx.x * 256 + threadIdx.x;
  long long base = t * 8;
  int row = (int)(base >> 9);
  int col = (int)(base & 511);
  long long src = (long long)tok[row] * 512 + col;
  float4 a = *(const float4*)(emb + src);
  float4 b = *(const float4*)(emb + src + 4);
  u16x8 o;
  o[0] = f2bf(a.x); o[1] = f2bf(a.y); o[2] = f2bf(a.z); o[3] = f2bf(a.w);
  o[4] = f2bf(b.x); o[5] = f2bf(b.y); o[6] = f2bf(b.z); o[7] = f2bf(b.w);
  *(u16x8*)(x + base) = o;
}

// ---------------- GEMM: xg = X @ Wih^T + bias, written in XGP layout ----------------
// XGP[t][m(2048)][h(256)][g(4)] (4 gates contiguous per (m,h)); slot t = dir ? 63-l : l, m = dir*1024+n.
__global__ __launch_bounds__(256) void k_gemm_xg(const u16* __restrict__ X, const u16* __restrict__ W,
                                                 const float* __restrict__ bias, u16* __restrict__ XGP) {
  __shared__ u16 Al[128 * 64];
  __shared__ u16 Bl[128 * 64];
  const int tid = threadIdx.x;
  const int wv = tid >> 6, lane = tid & 63;
  const int lr = lane & 15, lh = lane >> 4;
  const int bid = blockIdx.x;
  const int local = bid >> 3;
  const int bn = local & 15;
  const int bm = (bid & 7) * 64 + (local >> 4);
  f32x4 acc[2][8] = {};
  for (int kt = 0; kt < 8; ++kt) {
#pragma unroll
    for (int r = 0; r < 4; ++r) {
      int chunk = r * 4 + wv;
      int s = chunk * 1024 + lane * 16;
      int row = s >> 7;
      int kb = (s & 127) ^ ((row & 7) << 4);
      gl_lds16(X + (size_t)(bm * 128 + row) * 512 + kt * 64 + (kb >> 1), (char*)Al + chunk * 1024);
      gl_lds16(W + (size_t)(bn * 128 + row) * 512 + kt * 64 + (kb >> 1), (char*)Bl + chunk * 1024);
    }
    __syncthreads();
#pragma unroll
    for (int ks = 0; ks < 2; ++ks) {
      int kbf = ks * 64 + lh * 16;
      int ra = wv * 32 + lr;
      int xa = kbf ^ ((ra & 7) << 4);
      bf16x8 a0 = *(const bf16x8*)((const char*)Al + ra * 128 + xa);
      bf16x8 a1 = *(const bf16x8*)((const char*)Al + (ra + 16) * 128 + xa);
#pragma unroll
      for (int nj = 0; nj < 8; ++nj) {
        int c = nj * 16 + lr;
        bf16x8 b = *(const bf16x8*)((const char*)Bl + c * 128 + (kbf ^ ((c & 7) << 4)));
        acc[0][nj] = __builtin_amdgcn_mfma_f32_16x16x32_bf16(a0, b, acc[0][nj], 0, 0, 0);
        acc[1][nj] = __builtin_amdgcn_mfma_f32_16x16x32_bf16(a1, b, acc[1][nj], 0, 0, 0);
      }
    }
    __syncthreads();
  }
#pragma unroll
  for (int mi = 0; mi < 2; ++mi)
#pragma unroll
    for (int nj = 0; nj < 8; ++nj) {
      int col = bn * 128 + nj * 16 + lr;
      float bv = bias[col];
      int dirg = col >> 10, gg = (col >> 8) & 3, h = col & 255;
#pragma unroll
      for (int r = 0; r < 4; ++r) {
        int row = bm * 128 + wv * 32 + mi * 16 + lh * 4 + r;
        int n = row >> 6, l = row & 63;
        int tt = dirg ? (63 - l) : l;
        int m = dirg * 1024 + n;
        size_t idx = ((size_t)(tt * 2048 + m) * 256 + h) * 4 + gg;
        XGP[idx] = f2bf(acc[mi][nj][r] + bv);
      }
    }
}

// ---------------- image mean over 49 positions ----------------
__global__ __launch_bounds__(256) void k_imgmean(const float* __restrict__ img, u16* __restrict__ o) {
  int n = blockIdx.x;
  for (int j = 0; j < 2; ++j) {
    int col = threadIdx.x + j * 256;
    const float* p = img + (long long)n * 49 * 512 + col;
    float s = 0.f;
    for (int r = 0; r < 49; ++r) s += p[r * 512];
    o[(long long)n * 512 + col] = f2bf(s * (1.f / 49.f));
  }
}

// ---------------- image GEMM ----------------
__global__ __launch_bounds__(256) void k_gemm_img(const u16* __restrict__ A, const u16* __restrict__ W,
                                                  const float* __restrict__ bias, float* __restrict__ O) {
  __shared__ u16 Al[128 * 32];
  __shared__ u16 Bl[128 * 32];
  const int tid = threadIdx.x;
  const int wv = tid >> 6, lane = tid & 63;
  const int bm = blockIdx.x, bn = blockIdx.y;
  f32x4 acc[2][8] = {};
  const int lr = lane & 15, lk = (lane >> 4) * 8;
  for (int kt = 0; kt < 16; ++kt) {
    for (int i = 0; i < 2; ++i) {
      int lin = (wv * 2 + i) * 64 + lane;
      int r = lin >> 2, kc = lin & 3;
      int k = kt * 32 + kc * 8;
      gl_lds16(A + (long long)(bm * 128 + r) * 512 + k, &Al[(wv * 2 + i) * 512]);
      gl_lds16(W + (long long)(bn * 128 + r) * 512 + k, &Bl[(wv * 2 + i) * 512]);
    }
    __syncthreads();
    bf16x8 a0 = *(const bf16x8*)&Al[(wv * 32 + lr) * 32 + lk];
    bf16x8 a1 = *(const bf16x8*)&Al[(wv * 32 + 16 + lr) * 32 + lk];
    for (int nj = 0; nj < 8; ++nj) {
      bf16x8 b = *(const bf16x8*)&Bl[(nj * 16 + lr) * 32 + lk];
      acc[0][nj] = __builtin_amdgcn_mfma_f32_16x16x32_bf16(a0, b, acc[0][nj], 0, 0, 0);
      acc[1][nj] = __builtin_amdgcn_mfma_f32_16x16x32_bf16(a1, b, acc[1][nj], 0, 0, 0);
    }
    __syncthreads();
  }
  const int lh = lane >> 4;
  for (int mi = 0; mi < 2; ++mi)
    for (int nj = 0; nj < 8; ++nj) {
      int col = bn * 128 + nj * 16 + lr;
      float bv = bias[col];
      for (int r = 0; r < 4; ++r) {
        int row = bm * 128 + wv * 32 + mi * 16 + lh * 4 + r;
        O[(long long)row * 512 + col] = acc[mi][nj][r] + bv;
      }
    }
}

// ---------------- LSTM: identical structure to k_lstm6, but amdgpu_waves_per_eu(4,4) ----------------
// Dynamic LDS (144KB) caps the CU at 1 block = 4 waves/SIMD, but the compiler can't see that and
// targets 8 waves/EU -> 64 VGPR -> spills the ~105-reg live set into the step loop (r7/r8 evidence:
// VGPR_Count=64, VALUBusy 20% of bloat, 17K cy/step all-idle). waves_per_eu(4,4) pins the target
// at 4 waves/EU -> up to 128 VGPR -> live set fits, no spill.
__global__ __launch_bounds__(1024)
__attribute__((amdgpu_waves_per_eu(4, 4))) void k_lstm7(const u16* __restrict__ WP2,
                                                        const u16* __restrict__ XGP,
                                                        float* __restrict__ Hf) {
  extern __shared__ char lds[];
  const int tid = threadIdx.x;
  const int w = tid >> 6, l = tid & 63;
  const int l15 = l & 15, l4 = l >> 4;
  const int b = blockIdx.x;
  const int dir = b >> 6;
  const int m0 = (b & 63) * 16;
  const u16* wbase = WP2 + (((size_t)dir * 16 + w) * 8) * 2048;  // wave's 8 slabs x 4 frags x 512

  // ---- stage LDS slabs 2,3 once: 128 frags x 1 KB ----
#pragma unroll
  for (int i = 0; i < 8; ++i) {
    int chunk = i * 1024 + tid;
    int f = chunk >> 6;       // f = wR*8 + sl*4 + g
    int lane = chunk & 63;
    int wR = f >> 3, sl = (f >> 2) & 1, g = f & 3;
    const u16* src = WP2 + ((((size_t)dir * 16 + wR) * 8 + (2 + sl)) * 4 + g) * 512 + lane * 8;
    gl_lds16(src, lds + f * 1024 + lane * 16);
  }
  // ---- reg slabs 0,1 (8 frags = 32 VGPR) ----
  bf16x8 breg[2][4];
#pragma unroll
  for (int s = 0; s < 2; ++s)
#pragma unroll
    for (int g = 0; g < 4; ++g)
      breg[s][g] = *(const bf16x8*)(wbase + ((s * 4 + g) * 64 + l) * 8);
  // ---- zero both h buffers (16 KB) ----
  *(i32x4*)(lds + 131072 + tid * 16) = (i32x4){0, 0, 0, 0};
  __syncthreads();  // drains gl_lds too (compiler emits vmcnt(0) before barrier)

  float cst[4] = {};
  const int aswz = (l15 & 7) << 4;
  const int abase = l15 * 512;
#pragma unroll 1
  for (int t = 0; t < 64; ++t) {
    const char* hrd = lds + 131072 + (t & 1) * 8192;
    char* hwr = lds + 131072 + ((t + 1) & 1) * 8192;
    const u16* xgt = XGP + ((size_t)t * 2048 + dir * 1024 + m0) * 1024;
    // ---- early loads: stream slabs 4,5 + xg (latency hidden under MFMA section) ----
    bf16x8 bs0[4], bs1[4];
#pragma unroll
    for (int g = 0; g < 4; ++g) bs0[g] = *(const bf16x8*)(wbase + ((16 + g) * 64 + l) * 8);
#pragma unroll
    for (int g = 0; g < 4; ++g) bs1[g] = *(const bf16x8*)(wbase + ((20 + g) * 64 + l) * 8);
    u16x4 xv[4];
#pragma unroll
    for (int r = 0; r < 4; ++r)
      xv[r] = *(const u16x4*)(xgt + (l4 * 4 + r) * 1024 + (w * 16 + l15) * 4);
    f32x4 acc[4];
#pragma unroll
    for (int g = 0; g < 4; ++g) acc[g] = (f32x4){0.f, 0.f, 0.f, 0.f};
    // ---- slabs 0,1 (reg B) ----
#pragma unroll
    for (int s = 0; s < 2; ++s) {
      bf16x8 a = *(const bf16x8*)(hrd + abase + ((s * 64 + l4 * 16) ^ aswz));
#pragma unroll
      for (int g = 0; g < 4; ++g)
        acc[g] = __builtin_amdgcn_mfma_f32_16x16x32_bf16(a, breg[s][g], acc[g], 0, 0, 0);
    }
    // ---- slabs 2,3 (LDS B) ----
#pragma unroll
    for (int sl = 0; sl < 2; ++sl) {
      bf16x8 a = *(const bf16x8*)(hrd + abase + (((2 + sl) * 64 + l4 * 16) ^ aswz));
#pragma unroll
      for (int g = 0; g < 4; ++g) {
        bf16x8 bb = *(const bf16x8*)(lds + (w * 8 + sl * 4 + g) * 1024 + l * 16);
        acc[g] = __builtin_amdgcn_mfma_f32_16x16x32_bf16(a, bb, acc[g], 0, 0, 0);
      }
    }
    // ---- slab 4 (bs0), then refill bs0 <- slab 6 ----
    {
      bf16x8 a = *(const bf16x8*)(hrd + abase + ((4 * 64 + l4 * 16) ^ aswz));
#pragma unroll
      for (int g = 0; g < 4; ++g)
        acc[g] = __builtin_amdgcn_mfma_f32_16x16x32_bf16(a, bs0[g], acc[g], 0, 0, 0);
    }
#pragma unroll
    for (int g = 0; g < 4; ++g) bs0[g] = *(const bf16x8*)(wbase + ((24 + g) * 64 + l) * 8);
    // ---- slab 5 (bs1), then refill bs1 <- slab 7 ----
    {
      bf16x8 a = *(const bf16x8*)(hrd + abase + ((5 * 64 + l4 * 16) ^ aswz));
#pragma unroll
      for (int g = 0; g < 4; ++g)
        acc[g] = __builtin_amdgcn_mfma_f32_16x16x32_bf16(a, bs1[g], acc[g], 0, 0, 0);
    }
#pragma unroll
    for (int g = 0; g < 4; ++g) bs1[g] = *(const bf16x8*)(wbase + ((28 + g) * 64 + l) * 8);
    // ---- slab 6 (bs0), slab 7 (bs1) ----
    {
      bf16x8 a = *(const bf16x8*)(hrd + abase + ((6 * 64 + l4 * 16) ^ aswz));
#pragma unroll
      for (int g = 0; g < 4; ++g)
        acc[g] = __builtin_amdgcn_mfma_f32_16x16x32_bf16(a, bs0[g], acc[g], 0, 0, 0);
    }
    {
      bf16x8 a = *(const bf16x8*)(hrd + abase + ((7 * 64 + l4 * 16) ^ aswz));
#pragma unroll
      for (int g = 0; g < 4; ++g)
        acc[g] = __builtin_amdgcn_mfma_f32_16x16x32_bf16(a, bs1[g], acc[g], 0, 0, 0);
    }
    // ---- cell update (lane-local) ----
#pragma unroll
    for (int r = 0; r < 4; ++r) {
      float gi = acc[0][r] + bf2f(xv[r][0]);
      float gf = acc[1][r] + bf2f(xv[r][1]);
      float gg = acc[2][r] + bf2f(xv[r][2]);
      float go = acc[3][r] + bf2f(xv[r][3]);
      float cn = sigf(gf) * cst[r] + sigf(gi) * tanh_(gg);
      cst[r] = cn;
      float hn = sigf(go) * tanh_(cn);
      int row = l4 * 4 + r;
      int hcol = w * 16 + l15;
      if (t < 63)
        *(u16*)(hwr + row * 512 + ((2 * hcol) ^ ((row & 7) << 4))) = f2bf(hn);
      else
        Hf[(size_t)(dir * 1024 + m0 + row) * 256 + hcol] = hn;
    }
    __syncthreads();
  }
}

// ---------------- attention fusion + mean over tweets ----------------
__global__ __launch_bounds__(256) void k_fusion(const float* __restrict__ Hf, const float* __restrict__ IH,
                                                const float* __restrict__ WT, const float* __restrict__ WI,
                                                float* __restrict__ msum) {
  int wv = threadIdx.x >> 6, lane = threadIdx.x & 63;
  float facc[8] = {0.f, 0.f, 0.f, 0.f, 0.f, 0.f, 0.f, 0.f};
  for (int p = 0; p < 8; ++p) {
    int n = blockIdx.x * 32 + wv * 8 + p;
    float th[8], ih[8];
    float ts = 0.f, is = 0.f;
    for (int j = 0; j < 8; ++j) {
      int e = lane * 8 + j;
      float tv = (e < 256) ? Hf[(long long)n * 256 + e] : Hf[(long long)(1024 + n) * 256 + (e - 256)];
      float iv = IH[(long long)n * 512 + e];
      th[j] = tv; ih[j] = iv;
      ts += tv * WT[e];
      is += iv * WI[e];
    }
    for (int off = 32; off > 0; off >>= 1) {
      ts += __shfl_down(ts, off);
      is += __shfl_down(is, off);
    }
    ts = __shfl(ts, 0);
    is = __shfl(is, 0);
    float a0 = 1.f / (1.f + __expf(is - ts));
    float a1 = 1.f - a0;
    for (int j = 0; j < 8; ++j) facc[j] += a0 * th[j] + a1 * ih[j];
  }
  for (int j = 0; j < 8; ++j) atomicAdd(&msum[lane * 8 + j], facc[j]);
}

// ---------------- classifier MLP ----------------
__global__ __launch_bounds__(256) void k_cls(const float* __restrict__ msum, const float* __restrict__ Wc1,
                                             const float* __restrict__ bc1, const float* __restrict__ Wc2,
                                             const float* __restrict__ bc2, float* __restrict__ out) {
  __shared__ float mf[512];
  __shared__ float hdd[512];
  __shared__ float red[2][256];
  int tid = threadIdx.x;
  for (int j = tid; j < 512; j += 256) mf[j] = msum[j] * (1.f / 1024.f);
  __syncthreads();
  for (int j = tid; j < 512; j += 256) {
    const float* wr = Wc1 + (long long)j * 512;
    float s = bc1[j];
    for (int k = 0; k < 512; ++k) s += mf[k] * wr[k];
    hdd[j] = fmaxf(s, 0.f);
  }
  __syncthreads();
  float s0 = 0.f, s1 = 0.f;
  for (int k = tid; k < 512; k += 256) {
    s0 += hdd[k] * Wc2[k];
    s1 += hdd[k] * Wc2[512 + k];
  }
  red[0][tid] = s0;
  red[1][tid] = s1;
  __syncthreads();
  if (tid < 2) {
    float s = 0.f;
    for (int k = 0; k < 256; ++k) s += red[tid][k];
    out[tid] = s + bc2[tid];
  }
}

extern "C" void kernel_launch(void* const* d_in, const int* in_sizes, int n_in,
                              void* d_out, int out_size, void* d_ws, size_t ws_size,
                              hipStream_t stream) {
  const int* tokens = (const int*)d_in[0];
  const float* images = (const float*)d_in[1];
  const float* embed = (const float*)d_in[2];
  const float* Wih_f = (const float*)d_in[3];
  const float* Whh_f = (const float*)d_in[4];
  const float* bih_f = (const float*)d_in[5];
  const float* bhh_f = (const float*)d_in[6];
  const float* Wih_b = (const float*)d_in[7];
  const float* Whh_b = (const float*)d_in[8];
  const float* bih_b = (const float*)d_in[9];
  const float* bhh_b = (const float*)d_in[10];
  const float* Wimg = (const float*)d_in[11];
  const float* bimg = (const float*)d_in[12];
  const float* W_T = (const float*)d_in[13];
  const float* W_I = (const float*)d_in[14];
  const float* Wc1 = (const float*)d_in[15];
  const float* bc1 = (const float*)d_in[16];
  const float* Wc2 = (const float*)d_in[17];
  const float* bc2 = (const float*)d_in[18];
  float* out = (float*)d_out;

  char* ws = (char*)d_ws;
  size_t off = 0;
  auto alloc = [&](size_t bytes) -> void* {
    void* p = ws + off;
    off += (bytes + 255) & ~(size_t)255;
    return p;
  };
  u16* xbf = (u16*)alloc((size_t)M1 * 512 * 2);       // 64 MiB
  u16* xgp = (u16*)alloc((size_t)M1 * 2048 * 2);      // 256 MiB (XGP layout)
  u16* wih_bf = (u16*)alloc((size_t)2048 * 512 * 2);
  u16* wp = (u16*)alloc((size_t)2 * 262144 * 2);      // 1 MiB fragment-packed Whh
  u16* wimg_bf = (u16*)alloc((size_t)512 * 512 * 2);
  float* bias_a = (float*)alloc((size_t)2048 * 4);
  float* hf32 = (float*)alloc((size_t)2048 * 256 * 4);
  u16* im_bf = (u16*)alloc((size_t)1024 * 512 * 2);
  float* im_h = (float*)alloc((size_t)1024 * 512 * 4);
  float* msum = (float*)alloc((size_t)512 * 4);

  hipMemsetAsync(msum, 0, (size_t)512 * 4, stream);

  k_f2bf<<<512, 256, 0, stream>>>(Wih_f, wih_bf, 524288);
  k_f2bf<<<512, 256, 0, stream>>>(Wih_b, wih_bf + 1024 * 512, 524288);
  k_f2bf<<<256, 256, 0, stream>>>(Wimg, wimg_bf, 262144);
  k_prep_wp2<<<2048, 256, 0, stream>>>(Whh_f, Whh_b, wp);
  k_bias<<<8, 256, 0, stream>>>(bih_f, bhh_f, bih_b, bhh_b, bias_a);

  k_gather<<<16384, 256, 0, stream>>>(tokens, embed, xbf);
  k_gemm_xg<<<8192, 256, 0, stream>>>(xbf, wih_bf, bias_a, xgp);

  k_imgmean<<<1024, 256, 0, stream>>>(images, im_bf);
  k_gemm_img<<<dim3(8, 4), 256, 0, stream>>>(im_bf, wimg_bf, bimg, im_h);

  hipFuncSetAttribute((const void*)k_lstm7, hipFuncAttributeMaxDynamicSharedMemorySize, 147456);
  k_lstm7<<<128, 1024, 147456, stream>>>(wp, xgp, hf32);

  k_fusion<<<32, 256, 0, stream>>>(hf32, im_h, W_T, W_I, msum);
  k_cls<<<1, 256, 0, stream>>>(msum, Wc1, bc1, Wc2, bc2, out);
}

// Round 11
// 740.631 us; speedup vs baseline: 1.2035x; 1.2035x over previous
//
#include <hip/hip_runtime.h>

typedef unsigned short u16;
typedef unsigned int u32;
typedef __bf16 bf16x8 __attribute__((ext_vector_type(8)));
typedef float f32x4 __attribute__((ext_vector_type(4)));
typedef u16 u16x4 __attribute__((ext_vector_type(4)));
typedef u16 u16x8 __attribute__((ext_vector_type(8)));
typedef int i32x4 __attribute__((ext_vector_type(4)));

#define N_TW 1024
#define L_TOK 64
#define M1 (N_TW * L_TOK)

__device__ __forceinline__ u16 f2bf(float f) {
  u32 u = __builtin_bit_cast(u32, f);
  u += 0x7fffu + ((u >> 16) & 1u);
  return (u16)(u >> 16);
}
__device__ __forceinline__ float bf2f(u16 b) {
  u32 u = ((u32)b) << 16;
  return __builtin_bit_cast(float, u);
}
__device__ __forceinline__ void gl_lds16(const void* g, void* l) {
  __builtin_amdgcn_global_load_lds((const __attribute__((address_space(1))) u32*)g,
                                   (__attribute__((address_space(3))) u32*)l, 16, 0, 0);
}
__device__ __forceinline__ float sigf(float x) { return 1.f / (1.f + __expf(-x)); }
__device__ __forceinline__ float tanh_(float x) { return 1.f - 2.f / (__expf(2.f * x) + 1.f); }

// ---------------- prep: fp32 -> bf16 weight conversion ----------------
__global__ __launch_bounds__(256) void k_f2bf(const float* __restrict__ s, u16* __restrict__ d, int n) {
  int i = (blockIdx.x * 256 + threadIdx.x) * 4;
  if (i < n) {
    float4 v = *(const float4*)(s + i);
    u16x4 o;
    o.x = f2bf(v.x); o.y = f2bf(v.y); o.z = f2bf(v.z); o.w = f2bf(v.w);
    *(u16x4*)(d + i) = o;
  }
}

__global__ __launch_bounds__(256) void k_bias(const float* __restrict__ a, const float* __restrict__ b,
                                              const float* __restrict__ c, const float* __restrict__ d,
                                              float* __restrict__ o) {
  int i = blockIdx.x * 256 + threadIdx.x;  // 0..2047
  o[i] = (i < 1024) ? (a[i] + b[i]) : (c[i - 1024] + d[i - 1024]);
}

// ---------------- Whh pack for k_lstm8: WP3[dir][w(8)][s(8)][g(4)][c(2)][l(64)][i(8)] ----------------
// lane l of frag (w,s,g,c) holds B[gate=g][h = w*32 + c*16 + (l&15)][k = s*32 + (l>>4)*8 + i].
__global__ __launch_bounds__(256) void k_prep_wp3(const float* __restrict__ Wf, const float* __restrict__ Wb,
                                                  u16* __restrict__ P) {
  int e = blockIdx.x * 256 + threadIdx.x;  // 0..524287
  int i = e & 7, l = (e >> 3) & 63, c = (e >> 9) & 1, g = (e >> 10) & 3;
  int s = (e >> 12) & 7, w = (e >> 15) & 7, dir = e >> 18;
  int h = w * 32 + c * 16 + (l & 15);
  int k = s * 32 + ((l >> 4) << 3) + i;
  const float* W = dir ? Wb : Wf;
  P[e] = f2bf(W[(g * 256 + h) * 256 + k]);
}

// ---------------- embedding gather + bf16 convert ----------------
__global__ __launch_bounds__(256) void k_gather(const int* __restrict__ tok, const float* __restrict__ emb,
                                                u16* __restrict__ x) {
  long long t = (long long)blockIdx.x * 256 + threadIdx.x;
  long long base = t * 8;
  int row = (int)(base >> 9);
  int col = (int)(base & 511);
  long long src = (long long)tok[row] * 512 + col;
  float4 a = *(const float4*)(emb + src);
  float4 b = *(const float4*)(emb + src + 4);
  u16x8 o;
  o[0] = f2bf(a.x); o[1] = f2bf(a.y); o[2] = f2bf(a.z); o[3] = f2bf(a.w);
  o[4] = f2bf(b.x); o[5] = f2bf(b.y); o[6] = f2bf(b.z); o[7] = f2bf(b.w);
  *(u16x8*)(x + base) = o;
}

// ---------------- GEMM: xg = X @ Wih^T + bias, written in XGQ layout ----------------
// XGQ[t][dir][nblk(128)][nrow(8)][h(256)*4+g]: 8-tweet step slice contiguous per lstm block.
__global__ __launch_bounds__(256) void k_gemm_xg(const u16* __restrict__ X, const u16* __restrict__ W,
                                                 const float* __restrict__ bias, u16* __restrict__ XGQ) {
  __shared__ u16 Al[128 * 64];
  __shared__ u16 Bl[128 * 64];
  const int tid = threadIdx.x;
  const int wv = tid >> 6, lane = tid & 63;
  const int lr = lane & 15, lh = lane >> 4;
  const int bid = blockIdx.x;
  const int local = bid >> 3;
  const int bn = local & 15;
  const int bm = (bid & 7) * 64 + (local >> 4);
  f32x4 acc[2][8] = {};
  for (int kt = 0; kt < 8; ++kt) {
#pragma unroll
    for (int r = 0; r < 4; ++r) {
      int chunk = r * 4 + wv;
      int s = chunk * 1024 + lane * 16;
      int row = s >> 7;
      int kb = (s & 127) ^ ((row & 7) << 4);
      gl_lds16(X + (size_t)(bm * 128 + row) * 512 + kt * 64 + (kb >> 1), (char*)Al + chunk * 1024);
      gl_lds16(W + (size_t)(bn * 128 + row) * 512 + kt * 64 + (kb >> 1), (char*)Bl + chunk * 1024);
    }
    __syncthreads();
#pragma unroll
    for (int ks = 0; ks < 2; ++ks) {
      int kbf = ks * 64 + lh * 16;
      int ra = wv * 32 + lr;
      int xa = kbf ^ ((ra & 7) << 4);
      bf16x8 a0 = *(const bf16x8*)((const char*)Al + ra * 128 + xa);
      bf16x8 a1 = *(const bf16x8*)((const char*)Al + (ra + 16) * 128 + xa);
#pragma unroll
      for (int nj = 0; nj < 8; ++nj) {
        int c = nj * 16 + lr;
        bf16x8 b = *(const bf16x8*)((const char*)Bl + c * 128 + (kbf ^ ((c & 7) << 4)));
        acc[0][nj] = __builtin_amdgcn_mfma_f32_16x16x32_bf16(a0, b, acc[0][nj], 0, 0, 0);
        acc[1][nj] = __builtin_amdgcn_mfma_f32_16x16x32_bf16(a1, b, acc[1][nj], 0, 0, 0);
      }
    }
    __syncthreads();
  }
#pragma unroll
  for (int mi = 0; mi < 2; ++mi)
#pragma unroll
    for (int nj = 0; nj < 8; ++nj) {
      int col = bn * 128 + nj * 16 + lr;
      float bv = bias[col];
      int dirg = col >> 10, gg = (col >> 8) & 3, h = col & 255;
#pragma unroll
      for (int r = 0; r < 4; ++r) {
        int row = bm * 128 + wv * 32 + mi * 16 + lh * 4 + r;
        int n = row >> 6, ltok = row & 63;
        int tt = dirg ? (63 - ltok) : ltok;
        size_t idx = (((size_t)tt * 2 + dirg) * 128 + (n >> 3)) * 8192 + (size_t)(n & 7) * 1024 + h * 4 + gg;
        XGQ[idx] = f2bf(acc[mi][nj][r] + bv);
      }
    }
}

// ---------------- image mean over 49 positions ----------------
__global__ __launch_bounds__(256) void k_imgmean(const float* __restrict__ img, u16* __restrict__ o) {
  int n = blockIdx.x;
  for (int j = 0; j < 2; ++j) {
    int col = threadIdx.x + j * 256;
    const float* p = img + (long long)n * 49 * 512 + col;
    float s = 0.f;
    for (int r = 0; r < 49; ++r) s += p[r * 512];
    o[(long long)n * 512 + col] = f2bf(s * (1.f / 49.f));
  }
}

// ---------------- image GEMM ----------------
__global__ __launch_bounds__(256) void k_gemm_img(const u16* __restrict__ A, const u16* __restrict__ W,
                                                  const float* __restrict__ bias, float* __restrict__ O) {
  __shared__ u16 Al[128 * 32];
  __shared__ u16 Bl[128 * 32];
  const int tid = threadIdx.x;
  const int wv = tid >> 6, lane = tid & 63;
  const int bm = blockIdx.x, bn = blockIdx.y;
  f32x4 acc[2][8] = {};
  const int lr = lane & 15, lk = (lane >> 4) * 8;
  for (int kt = 0; kt < 16; ++kt) {
    for (int i = 0; i < 2; ++i) {
      int lin = (wv * 2 + i) * 64 + lane;
      int r = lin >> 2, kc = lin & 3;
      int k = kt * 32 + kc * 8;
      gl_lds16(A + (long long)(bm * 128 + r) * 512 + k, &Al[(wv * 2 + i) * 512]);
      gl_lds16(W + (long long)(bn * 128 + r) * 512 + k, &Bl[(wv * 2 + i) * 512]);
    }
    __syncthreads();
    bf16x8 a0 = *(const bf16x8*)&Al[(wv * 32 + lr) * 32 + lk];
    bf16x8 a1 = *(const bf16x8*)&Al[(wv * 32 + 16 + lr) * 32 + lk];
    for (int nj = 0; nj < 8; ++nj) {
      bf16x8 b = *(const bf16x8*)&Bl[(nj * 16 + lr) * 32 + lk];
      acc[0][nj] = __builtin_amdgcn_mfma_f32_16x16x32_bf16(a0, b, acc[0][nj], 0, 0, 0);
      acc[1][nj] = __builtin_amdgcn_mfma_f32_16x16x32_bf16(a1, b, acc[1][nj], 0, 0, 0);
    }
    __syncthreads();
  }
  const int lh = lane >> 4;
  for (int mi = 0; mi < 2; ++mi)
    for (int nj = 0; nj < 8; ++nj) {
      int col = bn * 128 + nj * 16 + lr;
      float bv = bias[col];
      for (int r = 0; r < 4; ++r) {
        int row = bm * 128 + wv * 32 + mi * 16 + lh * 4 + r;
        O[(long long)row * 512 + col] = acc[mi][nj][r] + bv;
      }
    }
}

// ---------------- LSTM k_lstm8: fully-resident weights, 8 tweets/block, cross-step prefetch ----------------
// 256 blocks x 512 thr (8 waves, 2/SIMD). dir = b>>7, 8 tweets n0 = (b&127)*8 (A rows 0-7 valid,
// rows 8-15 zero). Wave w: 32 h x 4 gates = 8 frags/slab. Weights: slabs 0-5 in regs (192 VGPR),
// slabs 6,7 LDS-resident (8 waves x 16 KB = 128 KB). After MFMA, v_permlane32_swap_b32 moves the
// c=1 half to lanes 32-63 -> each lane owns 4 cells (row=(l4&1)*4+r, col=w*32+(l4>>1)*16+l15).
// xv prefetched 1 step ahead, kept in flight across a RAW s_barrier (no vmcnt drain).
// LDS: [0,128K) W slabs 6,7 per-wave frag-packed (16 KB each); [128K,144K) h[2][16][256] bf16.
__global__ __launch_bounds__(512)
__attribute__((amdgpu_waves_per_eu(2, 2))) void k_lstm8(const u16* __restrict__ WP3,
                                                        const u16* __restrict__ XGQ,
                                                        float* __restrict__ Hf) {
  extern __shared__ char lds[];
  char* hbuf = lds + 131072;
  const int tid = threadIdx.x;
  const int w = tid >> 6, l = tid & 63;
  const int l15 = l & 15, l4 = l >> 4;
  const int b = blockIdx.x;
  const int dir = b >> 7;
  const int nblk = b & 127;
  const u16* wbase = WP3 + (size_t)dir * 262144 + (size_t)w * 32768;

  // ---- stage LDS slabs 6,7 (per wave: 16 frags x 1 KB, linear dest) [r10 bug: staged only 8] ----
#pragma unroll
  for (int j = 0; j < 16; ++j)
    gl_lds16(wbase + 6 * 4096 + j * 512 + l * 8, lds + w * 16384 + j * 1024);
  // ---- reg slabs 0..5 (48 frags = 192 VGPR) ----
  bf16x8 breg[6][4][2];
#pragma unroll
  for (int s = 0; s < 6; ++s)
#pragma unroll
    for (int g = 0; g < 4; ++g)
#pragma unroll
      for (int c = 0; c < 2; ++c)
        breg[s][g][c] = *(const bf16x8*)(wbase + (size_t)(((s * 4 + g) * 2 + c) * 64 + l) * 8);
  // ---- zero h dbuf (16 KB) ----
  *(i32x4*)(hbuf + tid * 16) = (i32x4){0, 0, 0, 0};
  *(i32x4*)(hbuf + 8192 + tid * 16) = (i32x4){0, 0, 0, 0};
  // ---- xv prefetch for t=0 ----
  const int xrow = (l4 & 1) * 4;                    // + r
  const int hcol = w * 32 + (l4 >> 1) * 16 + l15;   // this lane's h column after swap
  u16x4 xv[4];
  {
    const u16* xb = XGQ + (((size_t)dir) * 128 + nblk) * 8192 + hcol * 4;
#pragma unroll
    for (int r = 0; r < 4; ++r) xv[r] = *(const u16x4*)(xb + (xrow + r) * 1024);
  }
  __syncthreads();  // drains gl_lds + init stores once

  float cst[4] = {0.f, 0.f, 0.f, 0.f};
  const int aswz = (l15 & 7) << 4;
#pragma unroll 1
  for (int t = 0; t < 64; ++t) {
    const char* hrd = hbuf + (t & 1) * 8192;
    char* hwr = hbuf + ((t + 1) & 1) * 8192;
    f32x4 acc[4][2];
#pragma unroll
    for (int g = 0; g < 4; ++g) {
      acc[g][0] = (f32x4){0.f, 0.f, 0.f, 0.f};
      acc[g][1] = (f32x4){0.f, 0.f, 0.f, 0.f};
    }
    // ---- slabs 0..5: B from registers ----
#pragma unroll
    for (int s = 0; s < 6; ++s) {
      bf16x8 a = *(const bf16x8*)(hrd + l15 * 512 + ((s * 64 + l4 * 16) ^ aswz));
#pragma unroll
      for (int g = 0; g < 4; ++g) {
        acc[g][0] = __builtin_amdgcn_mfma_f32_16x16x32_bf16(a, breg[s][g][0], acc[g][0], 0, 0, 0);
        acc[g][1] = __builtin_amdgcn_mfma_f32_16x16x32_bf16(a, breg[s][g][1], acc[g][1], 0, 0, 0);
      }
    }
    // ---- slabs 6,7: B from LDS ----
#pragma unroll
    for (int sl = 0; sl < 2; ++sl) {
      bf16x8 a = *(const bf16x8*)(hrd + l15 * 512 + (((6 + sl) * 64 + l4 * 16) ^ aswz));
#pragma unroll
      for (int g = 0; g < 4; ++g)
#pragma unroll
        for (int c = 0; c < 2; ++c) {
          bf16x8 bb = *(const bf16x8*)(lds + w * 16384 + ((sl * 4 + g) * 2 + c) * 1024 + l * 16);
          acc[g][c] = __builtin_amdgcn_mfma_f32_16x16x32_bf16(a, bb, acc[g][c], 0, 0, 0);
        }
    }
    // ---- swap c=1 half to lanes 32-63, then 4 lane-local cells ----
#pragma unroll
    for (int r = 0; r < 4; ++r) {
      float z[4];
#pragma unroll
      for (int g = 0; g < 4; ++g) {
        u32 x = __builtin_bit_cast(u32, acc[g][0][r]);
        u32 y = __builtin_bit_cast(u32, acc[g][1][r]);
        asm("v_permlane32_swap_b32 %0, %1" : "+v"(x), "+v"(y));
        z[g] = __builtin_bit_cast(float, x);
      }
      float gi = z[0] + bf2f(xv[r][0]);
      float gf = z[1] + bf2f(xv[r][1]);
      float gg = z[2] + bf2f(xv[r][2]);
      float go = z[3] + bf2f(xv[r][3]);
      float cn = sigf(gf) * cst[r] + sigf(gi) * tanh_(gg);
      cst[r] = cn;
      float hn = sigf(go) * tanh_(cn);
      int row = xrow + r;
      if (t < 63)
        *(u16*)(hwr + row * 512 + ((hcol * 2) ^ ((row & 7) << 4))) = f2bf(hn);
      else
        Hf[(size_t)(dir * 1024 + nblk * 8 + row) * 256 + hcol] = hn;
    }
    // ---- prefetch xv for t+1 (stays in flight across the raw barrier) ----
    {
      int tn = (t < 63) ? t + 1 : 63;
      const u16* xb = XGQ + (((size_t)tn * 2 + dir) * 128 + nblk) * 8192 + hcol * 4;
#pragma unroll
      for (int r = 0; r < 4; ++r) xv[r] = *(const u16x4*)(xb + (xrow + r) * 1024);
    }
    // ---- raw barrier: drain LDS writes only, keep global loads flying ----
    asm volatile("s_waitcnt lgkmcnt(0)" ::: "memory");
    __builtin_amdgcn_sched_barrier(0);
    __builtin_amdgcn_s_barrier();
    __builtin_amdgcn_sched_barrier(0);
  }
}

// ---------------- attention fusion + mean over tweets ----------------
__global__ __launch_bounds__(256) void k_fusion(const float* __restrict__ Hf, const float* __restrict__ IH,
                                                const float* __restrict__ WT, const float* __restrict__ WI,
                                                float* __restrict__ msum) {
  int wv = threadIdx.x >> 6, lane = threadIdx.x & 63;
  float facc[8] = {0.f, 0.f, 0.f, 0.f, 0.f, 0.f, 0.f, 0.f};
  for (int p = 0; p < 8; ++p) {
    int n = blockIdx.x * 32 + wv * 8 + p;
    float th[8], ih[8];
    float ts = 0.f, is = 0.f;
    for (int j = 0; j < 8; ++j) {
      int e = lane * 8 + j;
      float tv = (e < 256) ? Hf[(long long)n * 256 + e] : Hf[(long long)(1024 + n) * 256 + (e - 256)];
      float iv = IH[(long long)n * 512 + e];
      th[j] = tv; ih[j] = iv;
      ts += tv * WT[e];
      is += iv * WI[e];
    }
    for (int off = 32; off > 0; off >>= 1) {
      ts += __shfl_down(ts, off);
      is += __shfl_down(is, off);
    }
    ts = __shfl(ts, 0);
    is = __shfl(is, 0);
    float a0 = 1.f / (1.f + __expf(is - ts));
    float a1 = 1.f - a0;
    for (int j = 0; j < 8; ++j) facc[j] += a0 * th[j] + a1 * ih[j];
  }
  for (int j = 0; j < 8; ++j) atomicAdd(&msum[lane * 8 + j], facc[j]);
}

// ---------------- classifier MLP ----------------
__global__ __launch_bounds__(256) void k_cls(const float* __restrict__ msum, const float* __restrict__ Wc1,
                                             const float* __restrict__ bc1, const float* __restrict__ Wc2,
                                             const float* __restrict__ bc2, float* __restrict__ out) {
  __shared__ float mf[512];
  __shared__ float hdd[512];
  __shared__ float red[2][256];
  int tid = threadIdx.x;
  for (int j = tid; j < 512; j += 256) mf[j] = msum[j] * (1.f / 1024.f);
  __syncthreads();
  for (int j = tid; j < 512; j += 256) {
    const float* wr = Wc1 + (long long)j * 512;
    float s = bc1[j];
    for (int k = 0; k < 512; ++k) s += mf[k] * wr[k];
    hdd[j] = fmaxf(s, 0.f);
  }
  __syncthreads();
  float s0 = 0.f, s1 = 0.f;
  for (int k = tid; k < 512; k += 256) {
    s0 += hdd[k] * Wc2[k];
    s1 += hdd[k] * Wc2[512 + k];
  }
  red[0][tid] = s0;
  red[1][tid] = s1;
  __syncthreads();
  if (tid < 2) {
    float s = 0.f;
    for (int k = 0; k < 256; ++k) s += red[tid][k];
    out[tid] = s + bc2[tid];
  }
}

extern "C" void kernel_launch(void* const* d_in, const int* in_sizes, int n_in,
                              void* d_out, int out_size, void* d_ws, size_t ws_size,
                              hipStream_t stream) {
  const int* tokens = (const int*)d_in[0];
  const float* images = (const float*)d_in[1];
  const float* embed = (const float*)d_in[2];
  const float* Wih_f = (const float*)d_in[3];
  const float* Whh_f = (const float*)d_in[4];
  const float* bih_f = (const float*)d_in[5];
  const float* bhh_f = (const float*)d_in[6];
  const float* Wih_b = (const float*)d_in[7];
  const float* Whh_b = (const float*)d_in[8];
  const float* bih_b = (const float*)d_in[9];
  const float* bhh_b = (const float*)d_in[10];
  const float* Wimg = (const float*)d_in[11];
  const float* bimg = (const float*)d_in[12];
  const float* W_T = (const float*)d_in[13];
  const float* W_I = (const float*)d_in[14];
  const float* Wc1 = (const float*)d_in[15];
  const float* bc1 = (const float*)d_in[16];
  const float* Wc2 = (const float*)d_in[17];
  const float* bc2 = (const float*)d_in[18];
  float* out = (float*)d_out;

  char* ws = (char*)d_ws;
  size_t off = 0;
  auto alloc = [&](size_t bytes) -> void* {
    void* p = ws + off;
    off += (bytes + 255) & ~(size_t)255;
    return p;
  };
  u16* xbf = (u16*)alloc((size_t)M1 * 512 * 2);       // 64 MiB
  u16* xgq = (u16*)alloc((size_t)M1 * 2048 * 2);      // 256 MiB (XGQ layout)
  u16* wih_bf = (u16*)alloc((size_t)2048 * 512 * 2);
  u16* wp = (u16*)alloc((size_t)2 * 262144 * 2);      // 1 MiB fragment-packed Whh
  u16* wimg_bf = (u16*)alloc((size_t)512 * 512 * 2);
  float* bias_a = (float*)alloc((size_t)2048 * 4);
  float* hf32 = (float*)alloc((size_t)2048 * 256 * 4);
  u16* im_bf = (u16*)alloc((size_t)1024 * 512 * 2);
  float* im_h = (float*)alloc((size_t)1024 * 512 * 4);
  float* msum = (float*)alloc((size_t)512 * 4);

  hipMemsetAsync(msum, 0, (size_t)512 * 4, stream);

  k_f2bf<<<512, 256, 0, stream>>>(Wih_f, wih_bf, 524288);
  k_f2bf<<<512, 256, 0, stream>>>(Wih_b, wih_bf + 1024 * 512, 524288);
  k_f2bf<<<256, 256, 0, stream>>>(Wimg, wimg_bf, 262144);
  k_prep_wp3<<<2048, 256, 0, stream>>>(Whh_f, Whh_b, wp);
  k_bias<<<8, 256, 0, stream>>>(bih_f, bhh_f, bih_b, bhh_b, bias_a);

  k_gather<<<16384, 256, 0, stream>>>(tokens, embed, xbf);
  k_gemm_xg<<<8192, 256, 0, stream>>>(xbf, wih_bf, bias_a, xgq);

  k_imgmean<<<1024, 256, 0, stream>>>(images, im_bf);
  k_gemm_img<<<dim3(8, 4), 256, 0, stream>>>(im_bf, wimg_bf, bimg, im_h);

  hipFuncSetAttribute((const void*)k_lstm8, hipFuncAttributeMaxDynamicSharedMemorySize, 147456);
  k_lstm8<<<256, 512, 147456, stream>>>(wp, xgq, hf32);

  k_fusion<<<32, 256, 0, stream>>>(hf32, im_h, W_T, W_I, msum);
  k_cls<<<1, 256, 0, stream>>>(msum, Wc1, bc1, Wc2, bc2, out);
}

// Round 12
// 591.767 us; speedup vs baseline: 1.5063x; 1.2516x over previous
//
#include <hip/hip_runtime.h>
#include <hip/hip_fp8.h>

typedef unsigned short u16;
typedef unsigned int u32;
typedef unsigned char u8;
typedef long f8frag;  // 64-bit: 8 fp8 elements (2 VGPRs)
typedef __bf16 bf16x8 __attribute__((ext_vector_type(8)));
typedef float f32x4 __attribute__((ext_vector_type(4)));
typedef u16 u16x4 __attribute__((ext_vector_type(4)));
typedef u16 u16x8 __attribute__((ext_vector_type(8)));
typedef int i32x4 __attribute__((ext_vector_type(4)));

#define N_TW 1024
#define L_TOK 64
#define M1 (N_TW * L_TOK)

__device__ __forceinline__ u16 f2bf(float f) {
  u32 u = __builtin_bit_cast(u32, f);
  u += 0x7fffu + ((u >> 16) & 1u);
  return (u16)(u >> 16);
}
__device__ __forceinline__ float bf2f(u16 b) {
  u32 u = ((u32)b) << 16;
  return __builtin_bit_cast(float, u);
}
__device__ __forceinline__ void gl_lds16(const void* g, void* l) {
  __builtin_amdgcn_global_load_lds((const __attribute__((address_space(1))) u32*)g,
                                   (__attribute__((address_space(3))) u32*)l, 16, 0, 0);
}
__device__ __forceinline__ float sigf(float x) { return 1.f / (1.f + __expf(-x)); }
__device__ __forceinline__ float tanh_(float x) { return 1.f - 2.f / (__expf(2.f * x) + 1.f); }

// ---------------- prep: fp32 -> bf16 weight conversion ----------------
__global__ __launch_bounds__(256) void k_f2bf(const float* __restrict__ s, u16* __restrict__ d, int n) {
  int i = (blockIdx.x * 256 + threadIdx.x) * 4;
  if (i < n) {
    float4 v = *(const float4*)(s + i);
    u16x4 o;
    o.x = f2bf(v.x); o.y = f2bf(v.y); o.z = f2bf(v.z); o.w = f2bf(v.w);
    *(u16x4*)(d + i) = o;
  }
}

__global__ __launch_bounds__(256) void k_bias(const float* __restrict__ a, const float* __restrict__ b,
                                              const float* __restrict__ c, const float* __restrict__ d,
                                              float* __restrict__ o) {
  int i = blockIdx.x * 256 + threadIdx.x;  // 0..2047
  o[i] = (i < 1024) ? (a[i] + b[i]) : (c[i - 1024] + d[i - 1024]);
}

// ---------------- Whh pack to fp8-e4m3 (x16 scale): WP4[dir][w(8)][s(8)][g(4)][c(2)][l(64)][i(8)] ----------------
// byte e: lane l of frag (w,s,g,c) byte i holds e4m3(16 * B[gate=g][h=w*32+c*16+(l&15)][k=s*32+(l>>4)*8+i]).
__global__ __launch_bounds__(256) void k_prep_wp4(const float* __restrict__ Wf, const float* __restrict__ Wb,
                                                  u8* __restrict__ P) {
  int e = blockIdx.x * 256 + threadIdx.x;  // 0..524287
  int i = e & 7, l = (e >> 3) & 63, c = (e >> 9) & 1, g = (e >> 10) & 3;
  int s = (e >> 12) & 7, w = (e >> 15) & 7, dir = e >> 18;
  int h = w * 32 + c * 16 + (l & 15);
  int k = s * 32 + ((l >> 4) << 3) + i;
  const float* W = dir ? Wb : Wf;
  __hip_fp8_e4m3 q(W[(g * 256 + h) * 256 + k] * 16.f);
  P[e] = q.__x;
}

// ---------------- embedding gather + bf16 convert ----------------
__global__ __launch_bounds__(256) void k_gather(const int* __restrict__ tok, const float* __restrict__ emb,
                                                u16* __restrict__ x) {
  long long t = (long long)blockIdx.x * 256 + threadIdx.x;
  long long base = t * 8;
  int row = (int)(base >> 9);
  int col = (int)(base & 511);
  long long src = (long long)tok[row] * 512 + col;
  float4 a = *(const float4*)(emb + src);
  float4 b = *(const float4*)(emb + src + 4);
  u16x8 o;
  o[0] = f2bf(a.x); o[1] = f2bf(a.y); o[2] = f2bf(a.z); o[3] = f2bf(a.w);
  o[4] = f2bf(b.x); o[5] = f2bf(b.y); o[6] = f2bf(b.z); o[7] = f2bf(b.w);
  *(u16x8*)(x + base) = o;
}

// ---------------- GEMM: xg = X @ Wih^T + bias, written in XGQ layout ----------------
// XGQ[t][dir][nblk(128)][nrow(8)][h(256)*4+g]: 8-tweet step slice contiguous per lstm block.
__global__ __launch_bounds__(256) void k_gemm_xg(const u16* __restrict__ X, const u16* __restrict__ W,
                                                 const float* __restrict__ bias, u16* __restrict__ XGQ) {
  __shared__ u16 Al[128 * 64];
  __shared__ u16 Bl[128 * 64];
  const int tid = threadIdx.x;
  const int wv = tid >> 6, lane = tid & 63;
  const int lr = lane & 15, lh = lane >> 4;
  const int bid = blockIdx.x;
  const int local = bid >> 3;
  const int bn = local & 15;
  const int bm = (bid & 7) * 64 + (local >> 4);
  f32x4 acc[2][8] = {};
  for (int kt = 0; kt < 8; ++kt) {
#pragma unroll
    for (int r = 0; r < 4; ++r) {
      int chunk = r * 4 + wv;
      int s = chunk * 1024 + lane * 16;
      int row = s >> 7;
      int kb = (s & 127) ^ ((row & 7) << 4);
      gl_lds16(X + (size_t)(bm * 128 + row) * 512 + kt * 64 + (kb >> 1), (char*)Al + chunk * 1024);
      gl_lds16(W + (size_t)(bn * 128 + row) * 512 + kt * 64 + (kb >> 1), (char*)Bl + chunk * 1024);
    }
    __syncthreads();
#pragma unroll
    for (int ks = 0; ks < 2; ++ks) {
      int kbf = ks * 64 + lh * 16;
      int ra = wv * 32 + lr;
      int xa = kbf ^ ((ra & 7) << 4);
      bf16x8 a0 = *(const bf16x8*)((const char*)Al + ra * 128 + xa);
      bf16x8 a1 = *(const bf16x8*)((const char*)Al + (ra + 16) * 128 + xa);
#pragma unroll
      for (int nj = 0; nj < 8; ++nj) {
        int c = nj * 16 + lr;
        bf16x8 b = *(const bf16x8*)((const char*)Bl + c * 128 + (kbf ^ ((c & 7) << 4)));
        acc[0][nj] = __builtin_amdgcn_mfma_f32_16x16x32_bf16(a0, b, acc[0][nj], 0, 0, 0);
        acc[1][nj] = __builtin_amdgcn_mfma_f32_16x16x32_bf16(a1, b, acc[1][nj], 0, 0, 0);
      }
    }
    __syncthreads();
  }
#pragma unroll
  for (int mi = 0; mi < 2; ++mi)
#pragma unroll
    for (int nj = 0; nj < 8; ++nj) {
      int col = bn * 128 + nj * 16 + lr;
      float bv = bias[col];
      int dirg = col >> 10, gg = (col >> 8) & 3, h = col & 255;
#pragma unroll
      for (int r = 0; r < 4; ++r) {
        int row = bm * 128 + wv * 32 + mi * 16 + lh * 4 + r;
        int n = row >> 6, ltok = row & 63;
        int tt = dirg ? (63 - ltok) : ltok;
        size_t idx = (((size_t)tt * 2 + dirg) * 128 + (n >> 3)) * 8192 + (size_t)(n & 7) * 1024 + h * 4 + gg;
        XGQ[idx] = f2bf(acc[mi][nj][r] + bv);
      }
    }
}

// ---------------- image mean over 49 positions ----------------
__global__ __launch_bounds__(256) void k_imgmean(const float* __restrict__ img, u16* __restrict__ o) {
  int n = blockIdx.x;
  for (int j = 0; j < 2; ++j) {
    int col = threadIdx.x + j * 256;
    const float* p = img + (long long)n * 49 * 512 + col;
    float s = 0.f;
    for (int r = 0; r < 49; ++r) s += p[r * 512];
    o[(long long)n * 512 + col] = f2bf(s * (1.f / 49.f));
  }
}

// ---------------- image GEMM ----------------
__global__ __launch_bounds__(256) void k_gemm_img(const u16* __restrict__ A, const u16* __restrict__ W,
                                                  const float* __restrict__ bias, float* __restrict__ O) {
  __shared__ u16 Al[128 * 32];
  __shared__ u16 Bl[128 * 32];
  const int tid = threadIdx.x;
  const int wv = tid >> 6, lane = tid & 63;
  const int bm = blockIdx.x, bn = blockIdx.y;
  f32x4 acc[2][8] = {};
  const int lr = lane & 15, lk = (lane >> 4) * 8;
  for (int kt = 0; kt < 16; ++kt) {
    for (int i = 0; i < 2; ++i) {
      int lin = (wv * 2 + i) * 64 + lane;
      int r = lin >> 2, kc = lin & 3;
      int k = kt * 32 + kc * 8;
      gl_lds16(A + (long long)(bm * 128 + r) * 512 + k, &Al[(wv * 2 + i) * 512]);
      gl_lds16(W + (long long)(bn * 128 + r) * 512 + k, &Bl[(wv * 2 + i) * 512]);
    }
    __syncthreads();
    bf16x8 a0 = *(const bf16x8*)&Al[(wv * 32 + lr) * 32 + lk];
    bf16x8 a1 = *(const bf16x8*)&Al[(wv * 32 + 16 + lr) * 32 + lk];
    for (int nj = 0; nj < 8; ++nj) {
      bf16x8 b = *(const bf16x8*)&Bl[(nj * 16 + lr) * 32 + lk];
      acc[0][nj] = __builtin_amdgcn_mfma_f32_16x16x32_bf16(a0, b, acc[0][nj], 0, 0, 0);
      acc[1][nj] = __builtin_amdgcn_mfma_f32_16x16x32_bf16(a1, b, acc[1][nj], 0, 0, 0);
    }
    __syncthreads();
  }
  const int lh = lane >> 4;
  for (int mi = 0; mi < 2; ++mi)
    for (int nj = 0; nj < 8; ++nj) {
      int col = bn * 128 + nj * 16 + lr;
      float bv = bias[col];
      for (int r = 0; r < 4; ++r) {
        int row = bm * 128 + wv * 32 + mi * 16 + lh * 4 + r;
        O[(long long)row * 512 + col] = acc[mi][nj][r] + bv;
      }
    }
}

// ---------------- LSTM k_lstm9: fp8 fully-resident weights (regs 4 slabs + LDS 4 slabs) ----------------
// 256 blocks x 512 thr (8 waves). dir=b>>7, 8 tweets (A rows 0-7 valid, 8-15 zero).
// Scales: W x16 (prep), h x32 (quantize), acc x 1/512. MFMA fp8_fp8 16x16x32, same k-slab
// geometry as r11 bf16 (self-consistent A/B packing). permlane32_swap + lane-local cell as r11.
// LDS: [0,128K) W slabs 4-7 per-wave (16 KB each); [128K,+8448) h dbuf fp8 [2][16 rows][264 B].
__global__ __launch_bounds__(512)
__attribute__((amdgpu_waves_per_eu(2, 2))) void k_lstm9(const u8* __restrict__ WP4,
                                                        const u16* __restrict__ XGQ,
                                                        float* __restrict__ Hf) {
  extern __shared__ char lds[];
  char* hbuf = lds + 131072;
  const int tid = threadIdx.x;
  const int w = tid >> 6, l = tid & 63;
  const int l15 = l & 15, l4 = l >> 4;
  const int b = blockIdx.x;
  const int dir = b >> 7;
  const int nblk = b & 127;
  const u8* wbase = WP4 + (size_t)dir * 262144 + (size_t)w * 32768;

  // ---- stage LDS slabs 4..7 (per wave: 16 KB, linear dest) ----
#pragma unroll
  for (int j = 0; j < 16; ++j)
    gl_lds16(wbase + 16384 + j * 1024 + l * 16, lds + w * 16384 + j * 1024);
  // ---- reg slabs 0..3 (32 frags = 64 VGPR) ----
  f8frag breg[4][4][2];
#pragma unroll
  for (int s = 0; s < 4; ++s)
#pragma unroll
    for (int g = 0; g < 4; ++g)
#pragma unroll
      for (int c = 0; c < 2; ++c)
        breg[s][g][c] = *(const f8frag*)(wbase + ((s * 4 + g) * 2 + c) * 512 + l * 8);
  // ---- zero h dbuf (2 x 16 x 264 = 8448 B; rows 8-15 stay zero forever) ----
  for (int i = tid; i < 2112; i += 512) ((u32*)hbuf)[i] = 0;
  // ---- xv prefetch for t=0 ----
  const int xrow = (l4 & 1) * 4;                    // + r
  const int hcol = w * 32 + (l4 >> 1) * 16 + l15;   // lane's h column after swap
  u16x4 xv[4];
  {
    const u16* xb = XGQ + (((size_t)dir) * 128 + nblk) * 8192 + hcol * 4;
#pragma unroll
    for (int r = 0; r < 4; ++r) xv[r] = *(const u16x4*)(xb + (xrow + r) * 1024);
  }
  __syncthreads();  // drains gl_lds + init stores once

  float cst[4] = {0.f, 0.f, 0.f, 0.f};
  const float S = 1.f / 512.f;
#pragma unroll 1
  for (int t = 0; t < 64; ++t) {
    const char* hrd = hbuf + (t & 1) * 4224;
    char* hwr = hbuf + ((t + 1) & 1) * 4224;
    f32x4 acc[4][2];
#pragma unroll
    for (int g = 0; g < 4; ++g) {
      acc[g][0] = (f32x4){0.f, 0.f, 0.f, 0.f};
      acc[g][1] = (f32x4){0.f, 0.f, 0.f, 0.f};
    }
    // ---- slabs 0..3: B from registers ----
#pragma unroll
    for (int s = 0; s < 4; ++s) {
      f8frag a = *(const f8frag*)(hrd + l15 * 264 + s * 32 + l4 * 8);
#pragma unroll
      for (int g = 0; g < 4; ++g) {
        acc[g][0] = __builtin_amdgcn_mfma_f32_16x16x32_fp8_fp8(a, breg[s][g][0], acc[g][0], 0, 0, 0);
        acc[g][1] = __builtin_amdgcn_mfma_f32_16x16x32_fp8_fp8(a, breg[s][g][1], acc[g][1], 0, 0, 0);
      }
    }
    // ---- slabs 4..7: B from LDS ----
#pragma unroll
    for (int sl = 0; sl < 4; ++sl) {
      f8frag a = *(const f8frag*)(hrd + l15 * 264 + (4 + sl) * 32 + l4 * 8);
#pragma unroll
      for (int g = 0; g < 4; ++g)
#pragma unroll
        for (int c = 0; c < 2; ++c) {
          f8frag bb = *(const f8frag*)(lds + w * 16384 + ((sl * 4 + g) * 2 + c) * 512 + l * 8);
          acc[g][c] = __builtin_amdgcn_mfma_f32_16x16x32_fp8_fp8(a, bb, acc[g][c], 0, 0, 0);
        }
    }
    // ---- swap c=1 half to lanes 32-63, then 4 lane-local cells ----
#pragma unroll
    for (int r = 0; r < 4; ++r) {
      float z[4];
#pragma unroll
      for (int g = 0; g < 4; ++g) {
        u32 x = __builtin_bit_cast(u32, acc[g][0][r]);
        u32 y = __builtin_bit_cast(u32, acc[g][1][r]);
        asm("v_permlane32_swap_b32 %0, %1" : "+v"(x), "+v"(y));
        z[g] = __builtin_bit_cast(float, x);
      }
      float gi = z[0] * S + bf2f(xv[r][0]);
      float gf = z[1] * S + bf2f(xv[r][1]);
      float gg = z[2] * S + bf2f(xv[r][2]);
      float go = z[3] * S + bf2f(xv[r][3]);
      float cn = sigf(gf) * cst[r] + sigf(gi) * tanh_(gg);
      cst[r] = cn;
      float hn = sigf(go) * tanh_(cn);
      int row = xrow + r;
      if (t < 63) {
        __hip_fp8_e4m3 q(hn * 32.f);
        *(u8*)(hwr + row * 264 + hcol) = q.__x;
      } else {
        Hf[(size_t)(dir * 1024 + nblk * 8 + row) * 256 + hcol] = hn;
      }
    }
    // ---- prefetch xv for t+1 (stays in flight across the raw barrier) ----
    {
      int tn = (t < 63) ? t + 1 : 63;
      const u16* xb = XGQ + (((size_t)tn * 2 + dir) * 128 + nblk) * 8192 + hcol * 4;
#pragma unroll
      for (int r = 0; r < 4; ++r) xv[r] = *(const u16x4*)(xb + (xrow + r) * 1024);
    }
    // ---- raw barrier: drain LDS ops only, keep global loads flying ----
    asm volatile("s_waitcnt lgkmcnt(0)" ::: "memory");
    __builtin_amdgcn_sched_barrier(0);
    __builtin_amdgcn_s_barrier();
    __builtin_amdgcn_sched_barrier(0);
  }
}

// ---------------- attention fusion + mean over tweets ----------------
__global__ __launch_bounds__(256) void k_fusion(const float* __restrict__ Hf, const float* __restrict__ IH,
                                                const float* __restrict__ WT, const float* __restrict__ WI,
                                                float* __restrict__ msum) {
  int wv = threadIdx.x >> 6, lane = threadIdx.x & 63;
  float facc[8] = {0.f, 0.f, 0.f, 0.f, 0.f, 0.f, 0.f, 0.f};
  for (int p = 0; p < 8; ++p) {
    int n = blockIdx.x * 32 + wv * 8 + p;
    float th[8], ih[8];
    float ts = 0.f, is = 0.f;
    for (int j = 0; j < 8; ++j) {
      int e = lane * 8 + j;
      float tv = (e < 256) ? Hf[(long long)n * 256 + e] : Hf[(long long)(1024 + n) * 256 + (e - 256)];
      float iv = IH[(long long)n * 512 + e];
      th[j] = tv; ih[j] = iv;
      ts += tv * WT[e];
      is += iv * WI[e];
    }
    for (int off = 32; off > 0; off >>= 1) {
      ts += __shfl_down(ts, off);
      is += __shfl_down(is, off);
    }
    ts = __shfl(ts, 0);
    is = __shfl(is, 0);
    float a0 = 1.f / (1.f + __expf(is - ts));
    float a1 = 1.f - a0;
    for (int j = 0; j < 8; ++j) facc[j] += a0 * th[j] + a1 * ih[j];
  }
  for (int j = 0; j < 8; ++j) atomicAdd(&msum[lane * 8 + j], facc[j]);
}

// ---------------- classifier MLP ----------------
__global__ __launch_bounds__(256) void k_cls(const float* __restrict__ msum, const float* __restrict__ Wc1,
                                             const float* __restrict__ bc1, const float* __restrict__ Wc2,
                                             const float* __restrict__ bc2, float* __restrict__ out) {
  __shared__ float mf[512];
  __shared__ float hdd[512];
  __shared__ float red[2][256];
  int tid = threadIdx.x;
  for (int j = tid; j < 512; j += 256) mf[j] = msum[j] * (1.f / 1024.f);
  __syncthreads();
  for (int j = tid; j < 512; j += 256) {
    const float* wr = Wc1 + (long long)j * 512;
    float s = bc1[j];
    for (int k = 0; k < 512; ++k) s += mf[k] * wr[k];
    hdd[j] = fmaxf(s, 0.f);
  }
  __syncthreads();
  float s0 = 0.f, s1 = 0.f;
  for (int k = tid; k < 512; k += 256) {
    s0 += hdd[k] * Wc2[k];
    s1 += hdd[k] * Wc2[512 + k];
  }
  red[0][tid] = s0;
  red[1][tid] = s1;
  __syncthreads();
  if (tid < 2) {
    float s = 0.f;
    for (int k = 0; k < 256; ++k) s += red[tid][k];
    out[tid] = s + bc2[tid];
  }
}

extern "C" void kernel_launch(void* const* d_in, const int* in_sizes, int n_in,
                              void* d_out, int out_size, void* d_ws, size_t ws_size,
                              hipStream_t stream) {
  const int* tokens = (const int*)d_in[0];
  const float* images = (const float*)d_in[1];
  const float* embed = (const float*)d_in[2];
  const float* Wih_f = (const float*)d_in[3];
  const float* Whh_f = (const float*)d_in[4];
  const float* bih_f = (const float*)d_in[5];
  const float* bhh_f = (const float*)d_in[6];
  const float* Wih_b = (const float*)d_in[7];
  const float* Whh_b = (const float*)d_in[8];
  const float* bih_b = (const float*)d_in[9];
  const float* bhh_b = (const float*)d_in[10];
  const float* Wimg = (const float*)d_in[11];
  const float* bimg = (const float*)d_in[12];
  const float* W_T = (const float*)d_in[13];
  const float* W_I = (const float*)d_in[14];
  const float* Wc1 = (const float*)d_in[15];
  const float* bc1 = (const float*)d_in[16];
  const float* Wc2 = (const float*)d_in[17];
  const float* bc2 = (const float*)d_in[18];
  float* out = (float*)d_out;

  char* ws = (char*)d_ws;
  size_t off = 0;
  auto alloc = [&](size_t bytes) -> void* {
    void* p = ws + off;
    off += (bytes + 255) & ~(size_t)255;
    return p;
  };
  u16* xbf = (u16*)alloc((size_t)M1 * 512 * 2);       // 64 MiB
  u16* xgq = (u16*)alloc((size_t)M1 * 2048 * 2);      // 256 MiB (XGQ layout)
  u16* wih_bf = (u16*)alloc((size_t)2048 * 512 * 2);
  u8* wp = (u8*)alloc((size_t)2 * 262144);            // 512 KiB fp8 fragment-packed Whh
  u16* wimg_bf = (u16*)alloc((size_t)512 * 512 * 2);
  float* bias_a = (float*)alloc((size_t)2048 * 4);
  float* hf32 = (float*)alloc((size_t)2048 * 256 * 4);
  u16* im_bf = (u16*)alloc((size_t)1024 * 512 * 2);
  float* im_h = (float*)alloc((size_t)1024 * 512 * 4);
  float* msum = (float*)alloc((size_t)512 * 4);

  hipMemsetAsync(msum, 0, (size_t)512 * 4, stream);

  k_f2bf<<<512, 256, 0, stream>>>(Wih_f, wih_bf, 524288);
  k_f2bf<<<512, 256, 0, stream>>>(Wih_b, wih_bf + 1024 * 512, 524288);
  k_f2bf<<<256, 256, 0, stream>>>(Wimg, wimg_bf, 262144);
  k_prep_wp4<<<2048, 256, 0, stream>>>(Whh_f, Whh_b, wp);
  k_bias<<<8, 256, 0, stream>>>(bih_f, bhh_f, bih_b, bhh_b, bias_a);

  k_gather<<<16384, 256, 0, stream>>>(tokens, embed, xbf);
  k_gemm_xg<<<8192, 256, 0, stream>>>(xbf, wih_bf, bias_a, xgq);

  k_imgmean<<<1024, 256, 0, stream>>>(images, im_bf);
  k_gemm_img<<<dim3(8, 4), 256, 0, stream>>>(im_bf, wimg_bf, bimg, im_h);

  hipFuncSetAttribute((const void*)k_lstm9, hipFuncAttributeMaxDynamicSharedMemorySize, 139520);
  k_lstm9<<<256, 512, 139520, stream>>>(wp, xgq, hf32);

  k_fusion<<<32, 256, 0, stream>>>(hf32, im_h, W_T, W_I, msum);
  k_cls<<<1, 256, 0, stream>>>(msum, Wc1, bc1, Wc2, bc2, out);
}

// Round 13
// 507.871 us; speedup vs baseline: 1.7551x; 1.1652x over previous
//
#include <hip/hip_runtime.h>
#include <hip/hip_fp8.h>

typedef unsigned short u16;
typedef unsigned int u32;
typedef unsigned char u8;
typedef long f8frag;  // 64-bit: 8 fp8 elements (2 VGPRs)
typedef __bf16 bf16x8 __attribute__((ext_vector_type(8)));
typedef float f32x4 __attribute__((ext_vector_type(4)));
typedef u16 u16x4 __attribute__((ext_vector_type(4)));
typedef u16 u16x8 __attribute__((ext_vector_type(8)));
typedef u8 u8x4 __attribute__((ext_vector_type(4)));
typedef u8 u8x8 __attribute__((ext_vector_type(8)));
typedef int i32x4 __attribute__((ext_vector_type(4)));

#define N_TW 1024
#define L_TOK 64
#define M1 (N_TW * L_TOK)

__device__ __forceinline__ u16 f2bf(float f) {
  u32 u = __builtin_bit_cast(u32, f);
  u += 0x7fffu + ((u >> 16) & 1u);
  return (u16)(u >> 16);
}
__device__ __forceinline__ float bf2f(u16 b) {
  u32 u = ((u32)b) << 16;
  return __builtin_bit_cast(float, u);
}
__device__ __forceinline__ u8 f2f8(float f) {
  __hip_fp8_e4m3 q(f);
  return q.__x;
}
__device__ __forceinline__ float f82f(u8 b) {
  __hip_fp8_e4m3 q;
  q.__x = b;
  return (float)q;
}
__device__ __forceinline__ void gl_lds16(const void* g, void* l) {
  __builtin_amdgcn_global_load_lds((const __attribute__((address_space(1))) u32*)g,
                                   (__attribute__((address_space(3))) u32*)l, 16, 0, 0);
}
__device__ __forceinline__ float sigf(float x) { return 1.f / (1.f + __expf(-x)); }
__device__ __forceinline__ float tanh_(float x) { return 1.f - 2.f / (__expf(2.f * x) + 1.f); }

// ---------------- prep: fp32 -> bf16 / fp8 weight conversion ----------------
__global__ __launch_bounds__(256) void k_f2bf(const float* __restrict__ s, u16* __restrict__ d, int n) {
  int i = (blockIdx.x * 256 + threadIdx.x) * 4;
  if (i < n) {
    float4 v = *(const float4*)(s + i);
    u16x4 o;
    o.x = f2bf(v.x); o.y = f2bf(v.y); o.z = f2bf(v.z); o.w = f2bf(v.w);
    *(u16x4*)(d + i) = o;
  }
}

// fp32 -> fp8 e4m3 with x16 scale (for X and Wih)
__global__ __launch_bounds__(256) void k_f2f8(const float* __restrict__ s, u8* __restrict__ d, int n) {
  int i = (blockIdx.x * 256 + threadIdx.x) * 4;
  if (i < n) {
    float4 v = *(const float4*)(s + i);
    u8x4 o;
    o[0] = f2f8(v.x * 16.f); o[1] = f2f8(v.y * 16.f);
    o[2] = f2f8(v.z * 16.f); o[3] = f2f8(v.w * 16.f);
    *(u8x4*)(d + i) = o;
  }
}

__global__ __launch_bounds__(256) void k_bias(const float* __restrict__ a, const float* __restrict__ b,
                                              const float* __restrict__ c, const float* __restrict__ d,
                                              float* __restrict__ o) {
  int i = blockIdx.x * 256 + threadIdx.x;  // 0..2047
  o[i] = (i < 1024) ? (a[i] + b[i]) : (c[i - 1024] + d[i - 1024]);
}

// ---------------- Whh pack to fp8-e4m3 (x16 scale): WP4[dir][w(8)][s(8)][g(4)][c(2)][l(64)][i(8)] ----------------
__global__ __launch_bounds__(256) void k_prep_wp4(const float* __restrict__ Wf, const float* __restrict__ Wb,
                                                  u8* __restrict__ P) {
  int e = blockIdx.x * 256 + threadIdx.x;  // 0..524287
  int i = e & 7, l = (e >> 3) & 63, c = (e >> 9) & 1, g = (e >> 10) & 3;
  int s = (e >> 12) & 7, w = (e >> 15) & 7, dir = e >> 18;
  int h = w * 32 + c * 16 + (l & 15);
  int k = s * 32 + ((l >> 4) << 3) + i;
  const float* W = dir ? Wb : Wf;
  P[e] = f2f8(W[(g * 256 + h) * 256 + k] * 16.f);
}

// ---------------- embedding gather + fp8 convert (x16) ----------------
__global__ __launch_bounds__(256) void k_gather8(const int* __restrict__ tok, const float* __restrict__ emb,
                                                 u8* __restrict__ x) {
  long long t = (long long)blockIdx.x * 256 + threadIdx.x;
  long long base = t * 8;
  int row = (int)(base >> 9);
  int col = (int)(base & 511);
  long long src = (long long)tok[row] * 512 + col;
  float4 a = *(const float4*)(emb + src);
  float4 b = *(const float4*)(emb + src + 4);
  u8x8 o;
  o[0] = f2f8(a.x * 16.f); o[1] = f2f8(a.y * 16.f); o[2] = f2f8(a.z * 16.f); o[3] = f2f8(a.w * 16.f);
  o[4] = f2f8(b.x * 16.f); o[5] = f2f8(b.y * 16.f); o[6] = f2f8(b.z * 16.f); o[7] = f2f8(b.w * 16.f);
  *(u8x8*)(x + base) = o;
}

// ---------------- GEMM fp8: xg = X8 @ Wih8^T (x1/256) + bias -> fp8 x32, XGQ8 layout ----------------
// XGQ8[t][dir][nblk(128)][nrow(8)][h(256)*4+g] u8. 128x128 tile, BK=128 B rows, 4 kt iters.
__global__ __launch_bounds__(256) void k_gemm_xg8(const u8* __restrict__ X, const u8* __restrict__ W,
                                                  const float* __restrict__ bias, u8* __restrict__ XGQ) {
  __shared__ u8 Al[128 * 128];  // 16 KB
  __shared__ u8 Bl[128 * 128];
  const int tid = threadIdx.x;
  const int wv = tid >> 6, lane = tid & 63;
  const int lr = lane & 15, lh = lane >> 4;
  const int bid = blockIdx.x;
  const int local = bid >> 3;
  const int bn = local & 15;
  const int bm = (bid & 7) * 64 + (local >> 4);
  f32x4 acc[2][8] = {};
  for (int kt = 0; kt < 4; ++kt) {
#pragma unroll
    for (int r = 0; r < 4; ++r) {
      int s = (r * 256 + tid) * 16;
      int row = s >> 7;
      int kb = (s & 127) ^ ((row & 7) << 4);  // pre-swizzled global source (rule 21)
      gl_lds16(X + (size_t)(bm * 128 + row) * 512 + kt * 128 + kb, Al + s);
      gl_lds16(W + (size_t)(bn * 128 + row) * 512 + kt * 128 + kb, Bl + s);
    }
    __syncthreads();
#pragma unroll
    for (int ks = 0; ks < 4; ++ks) {
      int off = ks * 32 + lh * 8;
      int ra = wv * 32 + lr;
      f8frag a0 = *(const f8frag*)(Al + ra * 128 + (off ^ ((ra & 7) << 4)));
      f8frag a1 = *(const f8frag*)(Al + (ra + 16) * 128 + (off ^ (((ra + 16) & 7) << 4)));
#pragma unroll
      for (int nj = 0; nj < 8; ++nj) {
        int c = nj * 16 + lr;
        f8frag b = *(const f8frag*)(Bl + c * 128 + (off ^ ((c & 7) << 4)));
        acc[0][nj] = __builtin_amdgcn_mfma_f32_16x16x32_fp8_fp8(a0, b, acc[0][nj], 0, 0, 0);
        acc[1][nj] = __builtin_amdgcn_mfma_f32_16x16x32_fp8_fp8(a1, b, acc[1][nj], 0, 0, 0);
      }
    }
    __syncthreads();
  }
  const float SD = 1.f / 256.f;
#pragma unroll
  for (int mi = 0; mi < 2; ++mi)
#pragma unroll
    for (int nj = 0; nj < 8; ++nj) {
      int col = bn * 128 + nj * 16 + lr;
      float bv = bias[col];
      int dirg = col >> 10, gg = (col >> 8) & 3, h = col & 255;
#pragma unroll
      for (int r = 0; r < 4; ++r) {
        int row = bm * 128 + wv * 32 + mi * 16 + lh * 4 + r;
        int n = row >> 6, ltok = row & 63;
        int tt = dirg ? (63 - ltok) : ltok;
        size_t idx = (((size_t)tt * 2 + dirg) * 128 + (n >> 3)) * 8192 + (size_t)(n & 7) * 1024 + h * 4 + gg;
        XGQ[idx] = f2f8((acc[mi][nj][r] * SD + bv) * 32.f);
      }
    }
}

// ---------------- image mean over 49 positions ----------------
__global__ __launch_bounds__(256) void k_imgmean(const float* __restrict__ img, u16* __restrict__ o) {
  int n = blockIdx.x;
  for (int j = 0; j < 2; ++j) {
    int col = threadIdx.x + j * 256;
    const float* p = img + (long long)n * 49 * 512 + col;
    float s = 0.f;
    for (int r = 0; r < 49; ++r) s += p[r * 512];
    o[(long long)n * 512 + col] = f2bf(s * (1.f / 49.f));
  }
}

// ---------------- image GEMM (bf16, small) ----------------
__global__ __launch_bounds__(256) void k_gemm_img(const u16* __restrict__ A, const u16* __restrict__ W,
                                                  const float* __restrict__ bias, float* __restrict__ O) {
  __shared__ u16 Al[128 * 32];
  __shared__ u16 Bl[128 * 32];
  const int tid = threadIdx.x;
  const int wv = tid >> 6, lane = tid & 63;
  const int bm = blockIdx.x, bn = blockIdx.y;
  f32x4 acc[2][8] = {};
  const int lr = lane & 15, lk = (lane >> 4) * 8;
  for (int kt = 0; kt < 16; ++kt) {
    for (int i = 0; i < 2; ++i) {
      int lin = (wv * 2 + i) * 64 + lane;
      int r = lin >> 2, kc = lin & 3;
      int k = kt * 32 + kc * 8;
      gl_lds16(A + (long long)(bm * 128 + r) * 512 + k, &Al[(wv * 2 + i) * 512]);
      gl_lds16(W + (long long)(bn * 128 + r) * 512 + k, &Bl[(wv * 2 + i) * 512]);
    }
    __syncthreads();
    bf16x8 a0 = *(const bf16x8*)&Al[(wv * 32 + lr) * 32 + lk];
    bf16x8 a1 = *(const bf16x8*)&Al[(wv * 32 + 16 + lr) * 32 + lk];
    for (int nj = 0; nj < 8; ++nj) {
      bf16x8 b = *(const bf16x8*)&Bl[(nj * 16 + lr) * 32 + lk];
      acc[0][nj] = __builtin_amdgcn_mfma_f32_16x16x32_bf16(a0, b, acc[0][nj], 0, 0, 0);
      acc[1][nj] = __builtin_amdgcn_mfma_f32_16x16x32_bf16(a1, b, acc[1][nj], 0, 0, 0);
    }
    __syncthreads();
  }
  const int lh = lane >> 4;
  for (int mi = 0; mi < 2; ++mi)
    for (int nj = 0; nj < 8; ++nj) {
      int col = bn * 128 + nj * 16 + lr;
      float bv = bias[col];
      for (int r = 0; r < 4; ++r) {
        int row = bm * 128 + wv * 32 + mi * 16 + lh * 4 + r;
        O[(long long)row * 512 + col] = acc[mi][nj][r] + bv;
      }
    }
}

// ---------------- LSTM k_lstm9: fp8 fully-resident weights + fp8 xg stream (L3-resident) ----------------
// Identical structure to r12 (verified); xv is now u8x4 dequantized x1/32.
__global__ __launch_bounds__(512)
__attribute__((amdgpu_waves_per_eu(2, 2))) void k_lstm9(const u8* __restrict__ WP4,
                                                        const u8* __restrict__ XGQ,
                                                        float* __restrict__ Hf) {
  extern __shared__ char lds[];
  char* hbuf = lds + 131072;
  const int tid = threadIdx.x;
  const int w = tid >> 6, l = tid & 63;
  const int l15 = l & 15, l4 = l >> 4;
  const int b = blockIdx.x;
  const int dir = b >> 7;
  const int nblk = b & 127;
  const u8* wbase = WP4 + (size_t)dir * 262144 + (size_t)w * 32768;

  // ---- stage LDS slabs 4..7 (per wave: 16 KB, linear dest) ----
#pragma unroll
  for (int j = 0; j < 16; ++j)
    gl_lds16(wbase + 16384 + j * 1024 + l * 16, lds + w * 16384 + j * 1024);
  // ---- reg slabs 0..3 (32 frags = 64 VGPR) ----
  f8frag breg[4][4][2];
#pragma unroll
  for (int s = 0; s < 4; ++s)
#pragma unroll
    for (int g = 0; g < 4; ++g)
#pragma unroll
      for (int c = 0; c < 2; ++c)
        breg[s][g][c] = *(const f8frag*)(wbase + ((s * 4 + g) * 2 + c) * 512 + l * 8);
  // ---- zero h dbuf (2 x 16 x 264 = 8448 B; rows 8-15 stay zero forever) ----
  for (int i = tid; i < 2112; i += 512) ((u32*)hbuf)[i] = 0;
  // ---- xv prefetch for t=0 ----
  const int xrow = (l4 & 1) * 4;                    // + r
  const int hcol = w * 32 + (l4 >> 1) * 16 + l15;   // lane's h column after swap
  u8x4 xv[4];
  {
    const u8* xb = XGQ + (((size_t)dir) * 128 + nblk) * 8192 + hcol * 4;
#pragma unroll
    for (int r = 0; r < 4; ++r) xv[r] = *(const u8x4*)(xb + (xrow + r) * 1024);
  }
  __syncthreads();  // drains gl_lds + init stores once

  float cst[4] = {0.f, 0.f, 0.f, 0.f};
  const float S = 1.f / 512.f;
  const float SX = 1.f / 32.f;
#pragma unroll 1
  for (int t = 0; t < 64; ++t) {
    const char* hrd = hbuf + (t & 1) * 4224;
    char* hwr = hbuf + ((t + 1) & 1) * 4224;
    f32x4 acc[4][2];
#pragma unroll
    for (int g = 0; g < 4; ++g) {
      acc[g][0] = (f32x4){0.f, 0.f, 0.f, 0.f};
      acc[g][1] = (f32x4){0.f, 0.f, 0.f, 0.f};
    }
    // ---- slabs 0..3: B from registers ----
#pragma unroll
    for (int s = 0; s < 4; ++s) {
      f8frag a = *(const f8frag*)(hrd + l15 * 264 + s * 32 + l4 * 8);
#pragma unroll
      for (int g = 0; g < 4; ++g) {
        acc[g][0] = __builtin_amdgcn_mfma_f32_16x16x32_fp8_fp8(a, breg[s][g][0], acc[g][0], 0, 0, 0);
        acc[g][1] = __builtin_amdgcn_mfma_f32_16x16x32_fp8_fp8(a, breg[s][g][1], acc[g][1], 0, 0, 0);
      }
    }
    // ---- slabs 4..7: B from LDS ----
#pragma unroll
    for (int sl = 0; sl < 4; ++sl) {
      f8frag a = *(const f8frag*)(hrd + l15 * 264 + (4 + sl) * 32 + l4 * 8);
#pragma unroll
      for (int g = 0; g < 4; ++g)
#pragma unroll
        for (int c = 0; c < 2; ++c) {
          f8frag bb = *(const f8frag*)(lds + w * 16384 + ((sl * 4 + g) * 2 + c) * 512 + l * 8);
          acc[g][c] = __builtin_amdgcn_mfma_f32_16x16x32_fp8_fp8(a, bb, acc[g][c], 0, 0, 0);
        }
    }
    // ---- swap c=1 half to lanes 32-63, then 4 lane-local cells ----
#pragma unroll
    for (int r = 0; r < 4; ++r) {
      float z[4];
#pragma unroll
      for (int g = 0; g < 4; ++g) {
        u32 x = __builtin_bit_cast(u32, acc[g][0][r]);
        u32 y = __builtin_bit_cast(u32, acc[g][1][r]);
        asm("v_permlane32_swap_b32 %0, %1" : "+v"(x), "+v"(y));
        z[g] = __builtin_bit_cast(float, x);
      }
      float gi = z[0] * S + f82f(xv[r][0]) * SX;
      float gf = z[1] * S + f82f(xv[r][1]) * SX;
      float gg = z[2] * S + f82f(xv[r][2]) * SX;
      float go = z[3] * S + f82f(xv[r][3]) * SX;
      float cn = sigf(gf) * cst[r] + sigf(gi) * tanh_(gg);
      cst[r] = cn;
      float hn = sigf(go) * tanh_(cn);
      int row = xrow + r;
      if (t < 63) {
        *(u8*)(hwr + row * 264 + hcol) = f2f8(hn * 32.f);
      } else {
        Hf[(size_t)(dir * 1024 + nblk * 8 + row) * 256 + hcol] = hn;
      }
    }
    // ---- prefetch xv for t+1 (stays in flight across the raw barrier) ----
    {
      int tn = (t < 63) ? t + 1 : 63;
      const u8* xb = XGQ + (((size_t)tn * 2 + dir) * 128 + nblk) * 8192 + hcol * 4;
#pragma unroll
      for (int r = 0; r < 4; ++r) xv[r] = *(const u8x4*)(xb + (xrow + r) * 1024);
    }
    // ---- raw barrier: drain LDS ops only, keep global loads flying ----
    asm volatile("s_waitcnt lgkmcnt(0)" ::: "memory");
    __builtin_amdgcn_sched_barrier(0);
    __builtin_amdgcn_s_barrier();
    __builtin_amdgcn_sched_barrier(0);
  }
}

// ---------------- attention fusion + mean over tweets ----------------
__global__ __launch_bounds__(256) void k_fusion(const float* __restrict__ Hf, const float* __restrict__ IH,
                                                const float* __restrict__ WT, const float* __restrict__ WI,
                                                float* __restrict__ msum) {
  int wv = threadIdx.x >> 6, lane = threadIdx.x & 63;
  float facc[8] = {0.f, 0.f, 0.f, 0.f, 0.f, 0.f, 0.f, 0.f};
  for (int p = 0; p < 8; ++p) {
    int n = blockIdx.x * 32 + wv * 8 + p;
    float th[8], ih[8];
    float ts = 0.f, is = 0.f;
    for (int j = 0; j < 8; ++j) {
      int e = lane * 8 + j;
      float tv = (e < 256) ? Hf[(long long)n * 256 + e] : Hf[(long long)(1024 + n) * 256 + (e - 256)];
      float iv = IH[(long long)n * 512 + e];
      th[j] = tv; ih[j] = iv;
      ts += tv * WT[e];
      is += iv * WI[e];
    }
    for (int off = 32; off > 0; off >>= 1) {
      ts += __shfl_down(ts, off);
      is += __shfl_down(is, off);
    }
    ts = __shfl(ts, 0);
    is = __shfl(is, 0);
    float a0 = 1.f / (1.f + __expf(is - ts));
    float a1 = 1.f - a0;
    for (int j = 0; j < 8; ++j) facc[j] += a0 * th[j] + a1 * ih[j];
  }
  for (int j = 0; j < 8; ++j) atomicAdd(&msum[lane * 8 + j], facc[j]);
}

// ---------------- classifier MLP ----------------
__global__ __launch_bounds__(256) void k_cls(const float* __restrict__ msum, const float* __restrict__ Wc1,
                                             const float* __restrict__ bc1, const float* __restrict__ Wc2,
                                             const float* __restrict__ bc2, float* __restrict__ out) {
  __shared__ float mf[512];
  __shared__ float hdd[512];
  __shared__ float red[2][256];
  int tid = threadIdx.x;
  for (int j = tid; j < 512; j += 256) mf[j] = msum[j] * (1.f / 1024.f);
  __syncthreads();
  for (int j = tid; j < 512; j += 256) {
    const float* wr = Wc1 + (long long)j * 512;
    float s = bc1[j];
    for (int k = 0; k < 512; ++k) s += mf[k] * wr[k];
    hdd[j] = fmaxf(s, 0.f);
  }
  __syncthreads();
  float s0 = 0.f, s1 = 0.f;
  for (int k = tid; k < 512; k += 256) {
    s0 += hdd[k] * Wc2[k];
    s1 += hdd[k] * Wc2[512 + k];
  }
  red[0][tid] = s0;
  red[1][tid] = s1;
  __syncthreads();
  if (tid < 2) {
    float s = 0.f;
    for (int k = 0; k < 256; ++k) s += red[tid][k];
    out[tid] = s + bc2[tid];
  }
}

extern "C" void kernel_launch(void* const* d_in, const int* in_sizes, int n_in,
                              void* d_out, int out_size, void* d_ws, size_t ws_size,
                              hipStream_t stream) {
  const int* tokens = (const int*)d_in[0];
  const float* images = (const float*)d_in[1];
  const float* embed = (const float*)d_in[2];
  const float* Wih_f = (const float*)d_in[3];
  const float* Whh_f = (const float*)d_in[4];
  const float* bih_f = (const float*)d_in[5];
  const float* bhh_f = (const float*)d_in[6];
  const float* Wih_b = (const float*)d_in[7];
  const float* Whh_b = (const float*)d_in[8];
  const float* bih_b = (const float*)d_in[9];
  const float* bhh_b = (const float*)d_in[10];
  const float* Wimg = (const float*)d_in[11];
  const float* bimg = (const float*)d_in[12];
  const float* W_T = (const float*)d_in[13];
  const float* W_I = (const float*)d_in[14];
  const float* Wc1 = (const float*)d_in[15];
  const float* bc1 = (const float*)d_in[16];
  const float* Wc2 = (const float*)d_in[17];
  const float* bc2 = (const float*)d_in[18];
  float* out = (float*)d_out;

  char* ws = (char*)d_ws;
  size_t off = 0;
  auto alloc = [&](size_t bytes) -> void* {
    void* p = ws + off;
    off += (bytes + 255) & ~(size_t)255;
    return p;
  };
  u8* x8 = (u8*)alloc((size_t)M1 * 512);          // 32 MiB fp8 X
  u8* xgq = (u8*)alloc((size_t)M1 * 2048);        // 128 MiB fp8 XGQ (L3-resident)
  u8* wih8 = (u8*)alloc((size_t)2048 * 512);      // 1 MiB fp8 Wih
  u8* wp = (u8*)alloc((size_t)2 * 262144);        // 512 KiB fp8 fragment-packed Whh
  u16* wimg_bf = (u16*)alloc((size_t)512 * 512 * 2);
  float* bias_a = (float*)alloc((size_t)2048 * 4);
  float* hf32 = (float*)alloc((size_t)2048 * 256 * 4);
  u16* im_bf = (u16*)alloc((size_t)1024 * 512 * 2);
  float* im_h = (float*)alloc((size_t)1024 * 512 * 4);
  float* msum = (float*)alloc((size_t)512 * 4);

  hipMemsetAsync(msum, 0, (size_t)512 * 4, stream);

  k_f2f8<<<512, 256, 0, stream>>>(Wih_f, wih8, 524288);
  k_f2f8<<<512, 256, 0, stream>>>(Wih_b, wih8 + 1024 * 512, 524288);
  k_f2bf<<<256, 256, 0, stream>>>(Wimg, wimg_bf, 262144);
  k_prep_wp4<<<2048, 256, 0, stream>>>(Whh_f, Whh_b, wp);
  k_bias<<<8, 256, 0, stream>>>(bih_f, bhh_f, bih_b, bhh_b, bias_a);

  k_gather8<<<16384, 256, 0, stream>>>(tokens, embed, x8);
  k_gemm_xg8<<<8192, 256, 0, stream>>>(x8, wih8, bias_a, xgq);

  k_imgmean<<<1024, 256, 0, stream>>>(images, im_bf);
  k_gemm_img<<<dim3(8, 4), 256, 0, stream>>>(im_bf, wimg_bf, bimg, im_h);

  hipFuncSetAttribute((const void*)k_lstm9, hipFuncAttributeMaxDynamicSharedMemorySize, 139520);
  k_lstm9<<<256, 512, 139520, stream>>>(wp, xgq, hf32);

  k_fusion<<<32, 256, 0, stream>>>(hf32, im_h, W_T, W_I, msum);
  k_cls<<<1, 256, 0, stream>>>(msum, Wc1, bc1, Wc2, bc2, out);
}

// Round 14
// 494.578 us; speedup vs baseline: 1.8023x; 1.0269x over previous
//
#include <hip/hip_runtime.h>

typedef unsigned short u16;
typedef unsigned int u32;
typedef unsigned char u8;
typedef long f8frag;  // 64-bit: 8 fp8 elements (2 VGPRs)
typedef __bf16 bf16x8 __attribute__((ext_vector_type(8)));
typedef float f32x4 __attribute__((ext_vector_type(4)));
typedef u16 u16x4 __attribute__((ext_vector_type(4)));
typedef u16 u16x8 __attribute__((ext_vector_type(8)));
typedef u8 u8x4 __attribute__((ext_vector_type(4)));
typedef int i32x4 __attribute__((ext_vector_type(4)));

#define N_TW 1024
#define L_TOK 64
#define M1 (N_TW * L_TOK)

__device__ __forceinline__ u16 f2bf(float f) {
  u32 u = __builtin_bit_cast(u32, f);
  u += 0x7fffu + ((u >> 16) & 1u);
  return (u16)(u >> 16);
}
__device__ __forceinline__ float bf2f(u16 b) {
  u32 u = ((u32)b) << 16;
  return __builtin_bit_cast(float, u);
}
// HW fp8 e4m3 quant: v_cvt_pk_fp8_f32 (single value -> low byte)
__device__ __forceinline__ u8 f2f8(float f) {
  return (u8)(__builtin_amdgcn_cvt_pk_fp8_f32(f, f, 0, false) & 0xff);
}
__device__ __forceinline__ void gl_lds16(const void* g, void* l) {
  __builtin_amdgcn_global_load_lds((const __attribute__((address_space(1))) u32*)g,
                                   (__attribute__((address_space(3))) u32*)l, 16, 0, 0);
}
__device__ __forceinline__ float sigf(float x) { return 1.f / (1.f + __expf(-x)); }
__device__ __forceinline__ float tanh_(float x) { return 1.f - 2.f / (__expf(2.f * x) + 1.f); }

// ---------------- prep: fp32 -> bf16 / fp8 weight conversion ----------------
__global__ __launch_bounds__(256) void k_f2bf(const float* __restrict__ s, u16* __restrict__ d, int n) {
  int i = (blockIdx.x * 256 + threadIdx.x) * 4;
  if (i < n) {
    float4 v = *(const float4*)(s + i);
    u16x4 o;
    o.x = f2bf(v.x); o.y = f2bf(v.y); o.z = f2bf(v.z); o.w = f2bf(v.w);
    *(u16x4*)(d + i) = o;
  }
}

// fp32 -> fp8 e4m3 with x16 scale (for Wih), HW pack
__global__ __launch_bounds__(256) void k_f2f8(const float* __restrict__ s, u8* __restrict__ d, int n) {
  int i = (blockIdx.x * 256 + threadIdx.x) * 4;
  if (i < n) {
    float4 v = *(const float4*)(s + i);
    int w0 = __builtin_amdgcn_cvt_pk_fp8_f32(v.x * 16.f, v.y * 16.f, 0, false);
    w0 = __builtin_amdgcn_cvt_pk_fp8_f32(v.z * 16.f, v.w * 16.f, w0, true);
    *(u32*)(d + i) = (u32)w0;
  }
}

__global__ __launch_bounds__(256) void k_bias(const float* __restrict__ a, const float* __restrict__ b,
                                              const float* __restrict__ c, const float* __restrict__ d,
                                              float* __restrict__ o) {
  int i = blockIdx.x * 256 + threadIdx.x;  // 0..2047
  o[i] = (i < 1024) ? (a[i] + b[i]) : (c[i - 1024] + d[i - 1024]);
}

// ---------------- Whh pack to fp8-e4m3 (x16 scale): WP4[dir][w(8)][s(8)][g(4)][c(2)][l(64)][i(8)] ----------------
__global__ __launch_bounds__(256) void k_prep_wp4(const float* __restrict__ Wf, const float* __restrict__ Wb,
                                                  u8* __restrict__ P) {
  int e = blockIdx.x * 256 + threadIdx.x;  // 0..524287
  int i = e & 7, l = (e >> 3) & 63, c = (e >> 9) & 1, g = (e >> 10) & 3;
  int s = (e >> 12) & 7, w = (e >> 15) & 7, dir = e >> 18;
  int h = w * 32 + c * 16 + (l & 15);
  int k = s * 32 + ((l >> 4) << 3) + i;
  const float* W = dir ? Wb : Wf;
  P[e] = f2f8(W[(g * 256 + h) * 256 + k] * 16.f);
}

// ---------------- embedding gather + fp8 convert (x16), HW pack ----------------
__global__ __launch_bounds__(256) void k_gather8(const int* __restrict__ tok, const float* __restrict__ emb,
                                                 u8* __restrict__ x) {
  long long t = (long long)blockIdx.x * 256 + threadIdx.x;
  long long base = t * 8;
  int row = (int)(base >> 9);
  int col = (int)(base & 511);
  long long src = (long long)tok[row] * 512 + col;
  float4 a = *(const float4*)(emb + src);
  float4 b = *(const float4*)(emb + src + 4);
  int w0 = __builtin_amdgcn_cvt_pk_fp8_f32(a.x * 16.f, a.y * 16.f, 0, false);
  w0 = __builtin_amdgcn_cvt_pk_fp8_f32(a.z * 16.f, a.w * 16.f, w0, true);
  int w1 = __builtin_amdgcn_cvt_pk_fp8_f32(b.x * 16.f, b.y * 16.f, 0, false);
  w1 = __builtin_amdgcn_cvt_pk_fp8_f32(b.z * 16.f, b.w * 16.f, w1, true);
  *(u32*)(x + base) = (u32)w0;
  *(u32*)(x + base + 4) = (u32)w1;
}

// ---------------- GEMM fp8: xg = X8 @ Wih8^T (x1/256) + bias -> fp8 x32, XGQ8 layout ----------------
// XGQ8[t][dir][nblk(128)][nrow(8)][h(256)*4+g] u8. 128x128 tile, BK=128 B rows, 4 kt iters.
__global__ __launch_bounds__(256) void k_gemm_xg8(const u8* __restrict__ X, const u8* __restrict__ W,
                                                  const float* __restrict__ bias, u8* __restrict__ XGQ) {
  __shared__ u8 Al[128 * 128];  // 16 KB
  __shared__ u8 Bl[128 * 128];
  const int tid = threadIdx.x;
  const int wv = tid >> 6, lane = tid & 63;
  const int lr = lane & 15, lh = lane >> 4;
  const int bid = blockIdx.x;
  const int local = bid >> 3;
  const int bn = local & 15;
  const int bm = (bid & 7) * 64 + (local >> 4);
  f32x4 acc[2][8] = {};
  for (int kt = 0; kt < 4; ++kt) {
#pragma unroll
    for (int r = 0; r < 4; ++r) {
      int s = (r * 256 + tid) * 16;
      int row = s >> 7;
      int kb = (s & 127) ^ ((row & 7) << 4);  // pre-swizzled global source (rule 21)
      gl_lds16(X + (size_t)(bm * 128 + row) * 512 + kt * 128 + kb, Al + s);
      gl_lds16(W + (size_t)(bn * 128 + row) * 512 + kt * 128 + kb, Bl + s);
    }
    __syncthreads();
#pragma unroll
    for (int ks = 0; ks < 4; ++ks) {
      int off = ks * 32 + lh * 8;
      int ra = wv * 32 + lr;
      f8frag a0 = *(const f8frag*)(Al + ra * 128 + (off ^ ((ra & 7) << 4)));
      f8frag a1 = *(const f8frag*)(Al + (ra + 16) * 128 + (off ^ (((ra + 16) & 7) << 4)));
#pragma unroll
      for (int nj = 0; nj < 8; ++nj) {
        int c = nj * 16 + lr;
        f8frag b = *(const f8frag*)(Bl + c * 128 + (off ^ ((c & 7) << 4)));
        acc[0][nj] = __builtin_amdgcn_mfma_f32_16x16x32_fp8_fp8(a0, b, acc[0][nj], 0, 0, 0);
        acc[1][nj] = __builtin_amdgcn_mfma_f32_16x16x32_fp8_fp8(a1, b, acc[1][nj], 0, 0, 0);
      }
    }
    __syncthreads();
  }
  const float SD = 1.f / 256.f;
#pragma unroll
  for (int mi = 0; mi < 2; ++mi)
#pragma unroll
    for (int nj = 0; nj < 8; ++nj) {
      int col = bn * 128 + nj * 16 + lr;
      float bv = bias[col];
      int dirg = col >> 10, gg = (col >> 8) & 3, h = col & 255;
#pragma unroll
      for (int r = 0; r < 4; ++r) {
        int row = bm * 128 + wv * 32 + mi * 16 + lh * 4 + r;
        int n = row >> 6, ltok = row & 63;
        int tt = dirg ? (63 - ltok) : ltok;
        size_t idx = (((size_t)tt * 2 + dirg) * 128 + (n >> 3)) * 8192 + (size_t)(n & 7) * 1024 + h * 4 + gg;
        XGQ[idx] = f2f8((acc[mi][nj][r] * SD + bv) * 32.f);
      }
    }
}

// ---------------- image mean over 49 positions ----------------
__global__ __launch_bounds__(256) void k_imgmean(const float* __restrict__ img, u16* __restrict__ o) {
  int n = blockIdx.x;
  for (int j = 0; j < 2; ++j) {
    int col = threadIdx.x + j * 256;
    const float* p = img + (long long)n * 49 * 512 + col;
    float s = 0.f;
    for (int r = 0; r < 49; ++r) s += p[r * 512];
    o[(long long)n * 512 + col] = f2bf(s * (1.f / 49.f));
  }
}

// ---------------- image GEMM (bf16, small) ----------------
__global__ __launch_bounds__(256) void k_gemm_img(const u16* __restrict__ A, const u16* __restrict__ W,
                                                  const float* __restrict__ bias, float* __restrict__ O) {
  __shared__ u16 Al[128 * 32];
  __shared__ u16 Bl[128 * 32];
  const int tid = threadIdx.x;
  const int wv = tid >> 6, lane = tid & 63;
  const int bm = blockIdx.x, bn = blockIdx.y;
  f32x4 acc[2][8] = {};
  const int lr = lane & 15, lk = (lane >> 4) * 8;
  for (int kt = 0; kt < 16; ++kt) {
    for (int i = 0; i < 2; ++i) {
      int lin = (wv * 2 + i) * 64 + lane;
      int r = lin >> 2, kc = lin & 3;
      int k = kt * 32 + kc * 8;
      gl_lds16(A + (long long)(bm * 128 + r) * 512 + k, &Al[(wv * 2 + i) * 512]);
      gl_lds16(W + (long long)(bn * 128 + r) * 512 + k, &Bl[(wv * 2 + i) * 512]);
    }
    __syncthreads();
    bf16x8 a0 = *(const bf16x8*)&Al[(wv * 32 + lr) * 32 + lk];
    bf16x8 a1 = *(const bf16x8*)&Al[(wv * 32 + 16 + lr) * 32 + lk];
    for (int nj = 0; nj < 8; ++nj) {
      bf16x8 b = *(const bf16x8*)&Bl[(nj * 16 + lr) * 32 + lk];
      acc[0][nj] = __builtin_amdgcn_mfma_f32_16x16x32_bf16(a0, b, acc[0][nj], 0, 0, 0);
      acc[1][nj] = __builtin_amdgcn_mfma_f32_16x16x32_bf16(a1, b, acc[1][nj], 0, 0, 0);
    }
    __syncthreads();
  }
  const int lh = lane >> 4;
  for (int mi = 0; mi < 2; ++mi)
    for (int nj = 0; nj < 8; ++nj) {
      int col = bn * 128 + nj * 16 + lr;
      float bv = bias[col];
      for (int r = 0; r < 4; ++r) {
        int row = bm * 128 + wv * 32 + mi * 16 + lh * 4 + r;
        O[(long long)row * 512 + col] = acc[mi][nj][r] + bv;
      }
    }
}

// ---------------- LSTM k_lstm9: fp8 resident weights + fp8 xg stream, HW cvt ----------------
// Identical structure to r13 (verified); dequant/quant now via v_cvt_f32_fp8 / v_cvt_pk_fp8_f32.
__global__ __launch_bounds__(512)
__attribute__((amdgpu_waves_per_eu(2, 2))) void k_lstm9(const u8* __restrict__ WP4,
                                                        const u8* __restrict__ XGQ,
                                                        float* __restrict__ Hf) {
  extern __shared__ char lds[];
  char* hbuf = lds + 131072;
  const int tid = threadIdx.x;
  const int w = tid >> 6, l = tid & 63;
  const int l15 = l & 15, l4 = l >> 4;
  const int b = blockIdx.x;
  const int dir = b >> 7;
  const int nblk = b & 127;
  const u8* wbase = WP4 + (size_t)dir * 262144 + (size_t)w * 32768;

  // ---- stage LDS slabs 4..7 (per wave: 16 KB, linear dest) ----
#pragma unroll
  for (int j = 0; j < 16; ++j)
    gl_lds16(wbase + 16384 + j * 1024 + l * 16, lds + w * 16384 + j * 1024);
  // ---- reg slabs 0..3 (32 frags = 64 VGPR) ----
  f8frag breg[4][4][2];
#pragma unroll
  for (int s = 0; s < 4; ++s)
#pragma unroll
    for (int g = 0; g < 4; ++g)
#pragma unroll
      for (int c = 0; c < 2; ++c)
        breg[s][g][c] = *(const f8frag*)(wbase + ((s * 4 + g) * 2 + c) * 512 + l * 8);
  // ---- zero h dbuf (2 x 16 x 264 = 8448 B; rows 8-15 stay zero forever) ----
  for (int i = tid; i < 2112; i += 512) ((u32*)hbuf)[i] = 0;
  // ---- xv prefetch for t=0 ----
  const int xrow = (l4 & 1) * 4;                    // + r
  const int hcol = w * 32 + (l4 >> 1) * 16 + l15;   // lane's h column after swap
  int xv[4];
  {
    const u8* xb = XGQ + (((size_t)dir) * 128 + nblk) * 8192 + hcol * 4;
#pragma unroll
    for (int r = 0; r < 4; ++r) xv[r] = *(const int*)(xb + (xrow + r) * 1024);
  }
  __syncthreads();  // drains gl_lds + init stores once

  float cst[4] = {0.f, 0.f, 0.f, 0.f};
  const float S = 1.f / 512.f;
  const float SX = 1.f / 32.f;
#pragma unroll 1
  for (int t = 0; t < 64; ++t) {
    const char* hrd = hbuf + (t & 1) * 4224;
    char* hwr = hbuf + ((t + 1) & 1) * 4224;
    f32x4 acc[4][2];
#pragma unroll
    for (int g = 0; g < 4; ++g) {
      acc[g][0] = (f32x4){0.f, 0.f, 0.f, 0.f};
      acc[g][1] = (f32x4){0.f, 0.f, 0.f, 0.f};
    }
    // ---- slabs 0..3: B from registers ----
#pragma unroll
    for (int s = 0; s < 4; ++s) {
      f8frag a = *(const f8frag*)(hrd + l15 * 264 + s * 32 + l4 * 8);
#pragma unroll
      for (int g = 0; g < 4; ++g) {
        acc[g][0] = __builtin_amdgcn_mfma_f32_16x16x32_fp8_fp8(a, breg[s][g][0], acc[g][0], 0, 0, 0);
        acc[g][1] = __builtin_amdgcn_mfma_f32_16x16x32_fp8_fp8(a, breg[s][g][1], acc[g][1], 0, 0, 0);
      }
    }
    // ---- slabs 4..7: B from LDS ----
#pragma unroll
    for (int sl = 0; sl < 4; ++sl) {
      f8frag a = *(const f8frag*)(hrd + l15 * 264 + (4 + sl) * 32 + l4 * 8);
#pragma unroll
      for (int g = 0; g < 4; ++g)
#pragma unroll
        for (int c = 0; c < 2; ++c) {
          f8frag bb = *(const f8frag*)(lds + w * 16384 + ((sl * 4 + g) * 2 + c) * 512 + l * 8);
          acc[g][c] = __builtin_amdgcn_mfma_f32_16x16x32_fp8_fp8(a, bb, acc[g][c], 0, 0, 0);
        }
    }
    // ---- swap c=1 half to lanes 32-63, then 4 lane-local cells (HW fp8 cvt) ----
#pragma unroll
    for (int r = 0; r < 4; ++r) {
      float z[4];
#pragma unroll
      for (int g = 0; g < 4; ++g) {
        u32 x = __builtin_bit_cast(u32, acc[g][0][r]);
        u32 y = __builtin_bit_cast(u32, acc[g][1][r]);
        asm("v_permlane32_swap_b32 %0, %1" : "+v"(x), "+v"(y));
        z[g] = __builtin_bit_cast(float, x);
      }
      float gi = z[0] * S + __builtin_amdgcn_cvt_f32_fp8(xv[r], 0) * SX;
      float gf = z[1] * S + __builtin_amdgcn_cvt_f32_fp8(xv[r], 1) * SX;
      float gg = z[2] * S + __builtin_amdgcn_cvt_f32_fp8(xv[r], 2) * SX;
      float go = z[3] * S + __builtin_amdgcn_cvt_f32_fp8(xv[r], 3) * SX;
      float cn = sigf(gf) * cst[r] + sigf(gi) * tanh_(gg);
      cst[r] = cn;
      float hn = sigf(go) * tanh_(cn);
      int row = xrow + r;
      if (t < 63) {
        *(u8*)(hwr + row * 264 + hcol) = f2f8(hn * 32.f);
      } else {
        Hf[(size_t)(dir * 1024 + nblk * 8 + row) * 256 + hcol] = hn;
      }
    }
    // ---- prefetch xv for t+1 (stays in flight across the raw barrier) ----
    {
      int tn = (t < 63) ? t + 1 : 63;
      const u8* xb = XGQ + (((size_t)tn * 2 + dir) * 128 + nblk) * 8192 + hcol * 4;
#pragma unroll
      for (int r = 0; r < 4; ++r) xv[r] = *(const int*)(xb + (xrow + r) * 1024);
    }
    // ---- raw barrier: drain LDS ops only, keep global loads flying ----
    asm volatile("s_waitcnt lgkmcnt(0)" ::: "memory");
    __builtin_amdgcn_sched_barrier(0);
    __builtin_amdgcn_s_barrier();
    __builtin_amdgcn_sched_barrier(0);
  }
}

// ---------------- attention fusion + mean over tweets ----------------
__global__ __launch_bounds__(256) void k_fusion(const float* __restrict__ Hf, const float* __restrict__ IH,
                                                const float* __restrict__ WT, const float* __restrict__ WI,
                                                float* __restrict__ msum) {
  int wv = threadIdx.x >> 6, lane = threadIdx.x & 63;
  float facc[8] = {0.f, 0.f, 0.f, 0.f, 0.f, 0.f, 0.f, 0.f};
  for (int p = 0; p < 8; ++p) {
    int n = blockIdx.x * 32 + wv * 8 + p;
    float th[8], ih[8];
    float ts = 0.f, is = 0.f;
    for (int j = 0; j < 8; ++j) {
      int e = lane * 8 + j;
      float tv = (e < 256) ? Hf[(long long)n * 256 + e] : Hf[(long long)(1024 + n) * 256 + (e - 256)];
      float iv = IH[(long long)n * 512 + e];
      th[j] = tv; ih[j] = iv;
      ts += tv * WT[e];
      is += iv * WI[e];
    }
    for (int off = 32; off > 0; off >>= 1) {
      ts += __shfl_down(ts, off);
      is += __shfl_down(is, off);
    }
    ts = __shfl(ts, 0);
    is = __shfl(is, 0);
    float a0 = 1.f / (1.f + __expf(is - ts));
    float a1 = 1.f - a0;
    for (int j = 0; j < 8; ++j) facc[j] += a0 * th[j] + a1 * ih[j];
  }
  for (int j = 0; j < 8; ++j) atomicAdd(&msum[lane * 8 + j], facc[j]);
}

// ---------------- classifier MLP ----------------
__global__ __launch_bounds__(256) void k_cls(const float* __restrict__ msum, const float* __restrict__ Wc1,
                                             const float* __restrict__ bc1, const float* __restrict__ Wc2,
                                             const float* __restrict__ bc2, float* __restrict__ out) {
  __shared__ float mf[512];
  __shared__ float hdd[512];
  __shared__ float red[2][256];
  int tid = threadIdx.x;
  for (int j = tid; j < 512; j += 256) mf[j] = msum[j] * (1.f / 1024.f);
  __syncthreads();
  for (int j = tid; j < 512; j += 256) {
    const float* wr = Wc1 + (long long)j * 512;
    float s = bc1[j];
    for (int k = 0; k < 512; ++k) s += mf[k] * wr[k];
    hdd[j] = fmaxf(s, 0.f);
  }
  __syncthreads();
  float s0 = 0.f, s1 = 0.f;
  for (int k = tid; k < 512; k += 256) {
    s0 += hdd[k] * Wc2[k];
    s1 += hdd[k] * Wc2[512 + k];
  }
  red[0][tid] = s0;
  red[1][tid] = s1;
  __syncthreads();
  if (tid < 2) {
    float s = 0.f;
    for (int k = 0; k < 256; ++k) s += red[tid][k];
    out[tid] = s + bc2[tid];
  }
}

extern "C" void kernel_launch(void* const* d_in, const int* in_sizes, int n_in,
                              void* d_out, int out_size, void* d_ws, size_t ws_size,
                              hipStream_t stream) {
  const int* tokens = (const int*)d_in[0];
  const float* images = (const float*)d_in[1];
  const float* embed = (const float*)d_in[2];
  const float* Wih_f = (const float*)d_in[3];
  const float* Whh_f = (const float*)d_in[4];
  const float* bih_f = (const float*)d_in[5];
  const float* bhh_f = (const float*)d_in[6];
  const float* Wih_b = (const float*)d_in[7];
  const float* Whh_b = (const float*)d_in[8];
  const float* bih_b = (const float*)d_in[9];
  const float* bhh_b = (const float*)d_in[10];
  const float* Wimg = (const float*)d_in[11];
  const float* bimg = (const float*)d_in[12];
  const float* W_T = (const float*)d_in[13];
  const float* W_I = (const float*)d_in[14];
  const float* Wc1 = (const float*)d_in[15];
  const float* bc1 = (const float*)d_in[16];
  const float* Wc2 = (const float*)d_in[17];
  const float* bc2 = (const float*)d_in[18];
  float* out = (float*)d_out;

  char* ws = (char*)d_ws;
  size_t off = 0;
  auto alloc = [&](size_t bytes) -> void* {
    void* p = ws + off;
    off += (bytes + 255) & ~(size_t)255;
    return p;
  };
  u8* x8 = (u8*)alloc((size_t)M1 * 512);          // 32 MiB fp8 X
  u8* xgq = (u8*)alloc((size_t)M1 * 2048);        // 128 MiB fp8 XGQ (L3-resident)
  u8* wih8 = (u8*)alloc((size_t)2048 * 512);      // 1 MiB fp8 Wih
  u8* wp = (u8*)alloc((size_t)2 * 262144);        // 512 KiB fp8 fragment-packed Whh
  u16* wimg_bf = (u16*)alloc((size_t)512 * 512 * 2);
  float* bias_a = (float*)alloc((size_t)2048 * 4);
  float* hf32 = (float*)alloc((size_t)2048 * 256 * 4);
  u16* im_bf = (u16*)alloc((size_t)1024 * 512 * 2);
  float* im_h = (float*)alloc((size_t)1024 * 512 * 4);
  float* msum = (float*)alloc((size_t)512 * 4);

  hipMemsetAsync(msum, 0, (size_t)512 * 4, stream);

  k_f2f8<<<512, 256, 0, stream>>>(Wih_f, wih8, 524288);
  k_f2f8<<<512, 256, 0, stream>>>(Wih_b, wih8 + 1024 * 512, 524288);
  k_f2bf<<<256, 256, 0, stream>>>(Wimg, wimg_bf, 262144);
  k_prep_wp4<<<2048, 256, 0, stream>>>(Whh_f, Whh_b, wp);
  k_bias<<<8, 256, 0, stream>>>(bih_f, bhh_f, bih_b, bhh_b, bias_a);

  k_gather8<<<16384, 256, 0, stream>>>(tokens, embed, x8);
  k_gemm_xg8<<<8192, 256, 0, stream>>>(x8, wih8, bias_a, xgq);

  k_imgmean<<<1024, 256, 0, stream>>>(images, im_bf);
  k_gemm_img<<<dim3(8, 4), 256, 0, stream>>>(im_bf, wimg_bf, bimg, im_h);

  hipFuncSetAttribute((const void*)k_lstm9, hipFuncAttributeMaxDynamicSharedMemorySize, 139520);
  k_lstm9<<<256, 512, 139520, stream>>>(wp, xgq, hf32);

  k_fusion<<<32, 256, 0, stream>>>(hf32, im_h, W_T, W_I, msum);
  k_cls<<<1, 256, 0, stream>>>(msum, Wc1, bc1, Wc2, bc2, out);
}